// Round 4
// baseline (426.106 us; speedup 1.0000x reference)
//
#include <hip/hip_runtime.h>

#define TOK   131072
#define BWIN  512

typedef __attribute__((ext_vector_type(8))) short bf16x8;
typedef __attribute__((ext_vector_type(4))) short bf16x4;
typedef __attribute__((ext_vector_type(4))) float f32x4;

__device__ __forceinline__ unsigned short f2us(float f) {   // RNE f32->bf16 bits
  union { float f; unsigned int i; } x; x.f = f;
  return (unsigned short)((x.i + 0x7fffu + ((x.i >> 16) & 1u)) >> 16);
}
__device__ __forceinline__ unsigned cvtpk(float lo, float hi) {  // 2xf32 -> packed bf16
  unsigned r;
  asm("v_cvt_pk_bf16_f32 %0, %1, %2" : "=v"(r) : "v"(lo), "v"(hi));
  return r;
}
union U8 { uint2 u; bf16x4 v; };

// ---- fragment-order bf16 weight images in ws (short offsets) ----
// Each fragment = 512 shorts (1 KB): lane l owns shorts [l*8, l*8+8).
// W1:   frag(nc,ks,nt) : fc1 B-operand  -> 4*3*6 = 72 frags
// W2:   frag(nc,ks,nt) : fc2 B-operand  -> 72 frags
// QKV:  frag(h,ks,mt)  : qkv A-operand  -> 4*3*5 = 60 frags (rows>=72 zero)
// PROJ: frag(ks,nt)    : proj B-operand, full K=96 -> 3*6 = 18 frags
#define IW1   0
#define IW2   36864
#define IQKV  73728
#define IPROJ 104448
#define IMG_SHORTS 113664

// ---------------- P0a: build fragment-order bf16 weight images ----------------
__global__ __launch_bounds__(256) void k_prepw(
    const float* __restrict__ fc1_w, const float* __restrict__ fc2_w,
    const float* __restrict__ qkv_w, const float* __restrict__ proj_w,
    unsigned short* __restrict__ img) {
  int i = blockIdx.x * 256 + threadIdx.x;    // 0..113663
  const int l = (i >> 3) & 63, j = i & 7;
  const int quad = l >> 4, l15 = l & 15;
  float v = 0.f;
  if (i < 36864) {                                        // W1 fragments
    int f = i >> 9; int nc = f / 18, rem = f - nc * 18;
    int ks = rem / 6, nt = rem - ks * 6;
    v = fc1_w[(size_t)(nc * 96 + nt * 16 + l15) * 96 + ks * 32 + quad * 8 + j];
  } else if (i < 73728) {                                 // W2 fragments
    int f = (i - 36864) >> 9; int nc = f / 18, rem = f - nc * 18;
    int ks = rem / 6, nt = rem - ks * 6;
    v = fc2_w[(size_t)(nt * 16 + l15) * 384 + nc * 96 + ks * 32 + quad * 8 + j];
  } else if (i < 104448) {                                // QKV A-fragments
    int f = (i - 73728) >> 9; int h = f / 15, rem = f - h * 15;
    int ks = rem / 5, mt = rem - ks * 5;
    int e = mt * 16 + l15;
    if (e < 72) {
      int grp = e / 24, rr = e - grp * 24;
      v = qkv_w[(size_t)(grp * 96 + h * 24 + rr) * 96 + ks * 32 + quad * 8 + j];
    }
  } else {                                                // proj B-fragments (full K)
    int f = (i - 104448) >> 9; int ks = f / 6, nt = f - ks * 6;
    v = proj_w[(size_t)(nt * 16 + l15) * 96 + ks * 32 + quad * 8 + j];
  }
  img[i] = f2us(v);
}

// ------- P0b: LN1 + cyclic shift -> xn bf16 (window order), 2 thr/token ------
__global__ __launch_bounds__(256) void k_ln1(const float* __restrict__ x,
                                             const float* __restrict__ g,
                                             const float* __restrict__ b,
                                             unsigned short* __restrict__ xn) {
  const int r = threadIdx.x >> 1, hf = threadIdx.x & 1;
  const int t = blockIdx.x * 128 + r;
  const int b_ = t >> 8, n = t & 255;
  const int batch = b_ >> 8, wi = b_ & 255;
  const int wd = (wi >> 6) & 3, wh = (wi >> 4) & 3, ww = (wi >> 2) & 3, wt = wi & 3;
  const int aa = (n >> 6) & 3, bb = (n >> 4) & 3, cc = (n >> 2) & 3, dd = n & 3;
  const int sd = (wd * 4 + aa + 2) & 15, sh = (wh * 4 + bb + 2) & 15;
  const int sw = (ww * 4 + cc + 2) & 15, st = (wt * 4 + dd + 2) & 15;
  const size_t gg = ((((size_t)(batch * 16 + sd) * 16 + sh) * 16 + sw) * 16 + st);

  const float4* base = (const float4*)(x + gg * 96 + hf * 48);
  float v[48];
  float s = 0.f, q2 = 0.f;
  #pragma unroll
  for (int j = 0; j < 12; j++) {
    float4 f = base[j];
    v[4 * j] = f.x; v[4 * j + 1] = f.y; v[4 * j + 2] = f.z; v[4 * j + 3] = f.w;
    s += f.x + f.y + f.z + f.w;
    q2 += f.x * f.x + f.y * f.y + f.z * f.z + f.w * f.w;
  }
  s += __shfl_xor(s, 1); q2 += __shfl_xor(q2, 1);
  const float mu = s * (1.f / 96.f);
  const float var = q2 * (1.f / 96.f) - mu * mu;
  const float rs = rsqrtf(fmaxf(var, 0.f) + 1e-5f);
  unsigned int* row = (unsigned int*)xn + (size_t)t * 48 + hf * 24;
  #pragma unroll
  for (int jj = 0; jj < 24; jj++) {
    int k0 = hf * 48 + 2 * jj;
    float a0 = (v[2 * jj]     - mu) * rs * g[k0]     + b[k0];
    float a1 = (v[2 * jj + 1] - mu) * rs * g[k0 + 1] + b[k0 + 1];
    row[jj] = cvtpk(a0, a1);
  }
}

// ---- k_win: QKV + attention only; O (normalized, bf16) -> global window-order
// LDS: s_k [256][36] + s_vt [32][260] + labels = 35,328 B -> 4 blocks/CU
__global__ __launch_bounds__(256, 4) void k_win(
    const unsigned short* __restrict__ xn,
    const unsigned short* __restrict__ img,
    const float* __restrict__ qkv_b,
    unsigned short* __restrict__ og) {
  __shared__ __align__(16) short s_k[256 * 36];    // K  [tok][36], e 24..31 zero
  __shared__ __align__(16) short s_vt[32 * 260];   // V^T [e][tok], rows 24..31 zero
  __shared__ unsigned char s_lb[256];

  const int tid = threadIdx.x;
  const int w = tid >> 6, l = tid & 63, quad = l >> 4, l15 = l & 15;
  const int q0 = w * 64;                       // wave's 64-token strip
  const int b_ = blockIdx.x;
  const int wi = b_ & 255;
  const int wd = (wi >> 6) & 3, wh = (wi >> 4) & 3, ww = (wi >> 2) & 3, wt = wi & 3;
  const float scale = 0.20412414523193154f;    // 24^-0.5
  const f32x4 fz = {0.f, 0.f, 0.f, 0.f};

  // ---- phase 0: labels + zero pads ----
  {
    const int n = tid;
    const int aa = (n >> 6) & 3, bb = (n >> 4) & 3, cc = (n >> 2) & 3, dd = n & 3;
    const int p0 = wd * 4 + aa, p1 = wh * 4 + bb, p2 = ww * 4 + cc, p3 = wt * 4 + dd;
    const int r0 = p0 >= 14 ? 2 : (p0 >= 12 ? 1 : 0);
    const int r1 = p1 >= 14 ? 2 : (p1 >= 12 ? 1 : 0);
    const int r2 = p2 >= 14 ? 2 : (p2 >= 12 ? 1 : 0);
    const int r3 = p3 >= 14 ? 2 : (p3 >= 12 ? 1 : 0);
    s_lb[n] = (unsigned char)(((r0 * 3 + r1) * 3 + r2) * 3 + r3);
    *(uint2*)&s_k[n * 36 + 24] = make_uint2(0u, 0u);   // e 24..27
    *(uint2*)&s_k[n * 36 + 28] = make_uint2(0u, 0u);   // e 28..31
    unsigned int* vz = (unsigned int*)(s_vt + 24 * 260);
    for (int i = tid; i < 8 * 130; i += 256) vz[i] = 0u;  // V rows 24..31 = 0
  }
  __syncthreads();

  const unsigned short* xw = xn + (size_t)b_ * 256 * 96;
  const unsigned short* wq = img + IQKV;

  for (int h = 0; h < 4; h++) {
    // ---- QKV GEMM (swapped, x32): weights direct global->reg fragments ----
    f32x4 acc[5][4];
    #pragma unroll
    for (int mt = 0; mt < 5; mt++)
      #pragma unroll
      for (int nt = 0; nt < 4; nt++) acc[mt][nt] = fz;
    #pragma unroll
    for (int ks = 0; ks < 3; ks++) {
      bf16x8 aw[5];
      #pragma unroll
      for (int mt = 0; mt < 5; mt++)
        aw[mt] = *(const bf16x8*)(wq + ((h * 3 + ks) * 5 + mt) * 512 + l * 8);
      #pragma unroll
      for (int nt = 0; nt < 4; nt++) {
        bf16x8 bx = *(const bf16x8*)(xw + (size_t)(q0 + nt * 16 + l15) * 96 + ks * 32 + quad * 8);
        #pragma unroll
        for (int mt = 0; mt < 5; mt++)
          acc[mt][nt] = __builtin_amdgcn_mfma_f32_16x16x32_bf16(aw[mt], bx, acc[mt][nt], 0, 0, 0);
      }
    }
    // ---- Q: pack in-register (B-operand of 16x16x16, e chunks mt=0,1) ----
    U8 qq[2][4];
    #pragma unroll
    for (int mt = 0; mt < 2; mt++) {
      const int e0 = mt * 16 + quad * 4;
      float b0 = qkv_b[h * 24 + e0],     b1 = qkv_b[h * 24 + e0 + 1];
      float b2 = qkv_b[h * 24 + e0 + 2], b3 = qkv_b[h * 24 + e0 + 3];
      #pragma unroll
      for (int nt = 0; nt < 4; nt++) {
        qq[mt][nt].u.x = cvtpk((acc[mt][nt][0] + b0) * scale, (acc[mt][nt][1] + b1) * scale);
        qq[mt][nt].u.y = cvtpk((acc[mt][nt][2] + b2) * scale, (acc[mt][nt][3] + b3) * scale);
      }
    }
    // ---- scatter K (uint2) / V^T (shorts) to LDS ----
    #pragma unroll
    for (int mt = 1; mt < 5; mt++) {
      const int e0 = mt * 16 + quad * 4;
      #pragma unroll
      for (int nt = 0; nt < 4; nt++) {
        const int tok = q0 + nt * 16 + l15;
        if (e0 >= 24 && e0 < 48) {       // K
          const int e = e0 - 24;
          uint2 pk;
          pk.x = cvtpk(acc[mt][nt][0] + qkv_b[96 + h * 24 + e],
                       acc[mt][nt][1] + qkv_b[96 + h * 24 + e + 1]);
          pk.y = cvtpk(acc[mt][nt][2] + qkv_b[96 + h * 24 + e + 2],
                       acc[mt][nt][3] + qkv_b[96 + h * 24 + e + 3]);
          *(uint2*)&s_k[tok * 36 + e] = pk;
        } else if (e0 >= 48 && e0 < 72) {  // V^T
          const int e = e0 - 48;
          #pragma unroll
          for (int r = 0; r < 4; r++)
            s_vt[(e + r) * 260 + tok] = (short)f2us(acc[mt][nt][r] + qkv_b[192 + h * 24 + e + r]);
        }
      }
    }
    __syncthreads();                                           // K/V visible
    // ---- attention: per 16-query tile, P and Q never touch LDS ----
    #pragma unroll 1
    for (int mt4 = 0; mt4 < 4; mt4++) {
      const int qt0 = q0 + mt4 * 16;
      f32x4 sc[16];
      #pragma unroll
      for (int km = 0; km < 16; km++) sc[km] = fz;
      const bf16x4 bq0 = qq[0][mt4].v, bq1 = qq[1][mt4].v;
      __builtin_amdgcn_s_setprio(1);
      #pragma unroll
      for (int km = 0; km < 16; km++) {
        bf16x4 ak0 = *(const bf16x4*)&s_k[(km * 16 + l15) * 36 + quad * 4];
        bf16x4 ak1 = *(const bf16x4*)&s_k[(km * 16 + l15) * 36 + 16 + quad * 4];
        sc[km] = __builtin_amdgcn_mfma_f32_16x16x16bf16_1k(ak0, bq0, sc[km], 0, 0, 0);
        sc[km] = __builtin_amdgcn_mfma_f32_16x16x16bf16_1k(ak1, bq1, sc[km], 0, 0, 0);
      }
      __builtin_amdgcn_s_setprio(0);
      // ---- masked exp (in place) + in-register row-sum ----
      const unsigned lq = s_lb[qt0 + l15];
      float rsum = 0.f;
      #pragma unroll
      for (int km = 0; km < 16; km++) {
        unsigned lj = *(const unsigned*)&s_lb[km * 16 + quad * 4];
        float p0 = ((lj & 255u)         == lq) ? __expf(sc[km][0]) : 0.f;
        float p1 = (((lj >> 8) & 255u)  == lq) ? __expf(sc[km][1]) : 0.f;
        float p2 = (((lj >> 16) & 255u) == lq) ? __expf(sc[km][2]) : 0.f;
        float p3 = ((lj >> 24)          == lq) ? __expf(sc[km][3]) : 0.f;
        sc[km][0] = p0; sc[km][1] = p1; sc[km][2] = p2; sc[km][3] = p3;
        rsum += (p0 + p1) + (p2 + p3);
      }
      rsum += __shfl_xor(rsum, 16, 64);
      rsum += __shfl_xor(rsum, 32, 64);
      const float inv = 1.f / rsum;
      // ---- PV (x16): P fed straight from registers ----
      f32x4 ov0 = fz, ov1 = fz;
      __builtin_amdgcn_s_setprio(1);
      #pragma unroll
      for (int km = 0; km < 16; km++) {
        U8 bp;
        bp.u.x = cvtpk(sc[km][0], sc[km][1]);
        bp.u.y = cvtpk(sc[km][2], sc[km][3]);
        bf16x4 av0 = *(const bf16x4*)&s_vt[l15 * 260 + km * 16 + quad * 4];
        bf16x4 av1 = *(const bf16x4*)&s_vt[(16 + l15) * 260 + km * 16 + quad * 4];
        ov0 = __builtin_amdgcn_mfma_f32_16x16x16bf16_1k(av0, bp.v, ov0, 0, 0, 0);
        ov1 = __builtin_amdgcn_mfma_f32_16x16x16bf16_1k(av1, bp.v, ov1, 0, 0, 0);
      }
      __builtin_amdgcn_s_setprio(0);
      // ---- O (normalized, bf16) straight to global, window order ----
      uint2 o0, o1;
      o0.x = cvtpk(ov0[0] * inv, ov0[1] * inv);
      o0.y = cvtpk(ov0[2] * inv, ov0[3] * inv);
      o1.x = cvtpk(ov1[0] * inv, ov1[1] * inv);
      o1.y = cvtpk(ov1[2] * inv, ov1[3] * inv);
      size_t ob = ((size_t)b_ * 256 + qt0 + l15) * 96 + h * 24;
      *(uint2*)&og[ob + quad * 4] = o0;                  // e 0..15
      if (quad < 2) *(uint2*)&og[ob + 16 + quad * 4] = o1;  // e 16..23
    }
    __syncthreads();               // all waves done with s_k/s_vt for this head
  }
}

// ---- k_proj: out = x + O @ Wp^T + pb  (O window-order bf16, out spatial f32)
__global__ __launch_bounds__(256, 4) void k_proj(
    const unsigned short* __restrict__ og, const float* __restrict__ x,
    const unsigned short* __restrict__ img,
    const float* __restrict__ proj_b, float* __restrict__ out) {
  const int tid = threadIdx.x;
  const int w = tid >> 6, l = tid & 63, quad = l >> 4, l15 = l & 15;
  const int t0 = blockIdx.x * 128;
  const f32x4 fz = {0.f, 0.f, 0.f, 0.f};

  f32x4 acc[2][6];
  #pragma unroll
  for (int m = 0; m < 2; m++)
    #pragma unroll
    for (int nt = 0; nt < 6; nt++) acc[m][nt] = fz;

  #pragma unroll
  for (int ks = 0; ks < 3; ks++) {
    bf16x8 bw[6];
    #pragma unroll
    for (int nt = 0; nt < 6; nt++)
      bw[nt] = *(const bf16x8*)(img + IPROJ + (ks * 6 + nt) * 512 + l * 8);
    #pragma unroll
    for (int m = 0; m < 2; m++) {
      bf16x8 af = *(const bf16x8*)(og + (size_t)(t0 + w * 32 + m * 16 + l15) * 96 + ks * 32 + quad * 8);
      #pragma unroll
      for (int nt = 0; nt < 6; nt++)
        acc[m][nt] = __builtin_amdgcn_mfma_f32_16x16x32_bf16(af, bw[nt], acc[m][nt], 0, 0, 0);
    }
  }

  // ---- epilogue: window token -> spatial address; bias + residual ----
  #pragma unroll
  for (int m = 0; m < 2; m++) {
    #pragma unroll
    for (int r = 0; r < 4; r++) {
      const int T = t0 + w * 32 + m * 16 + quad * 4 + r;
      const int b_ = T >> 8, n = T & 255;
      const int batch = b_ >> 8, wi = b_ & 255;
      const int wd = (wi >> 6) & 3, wh = (wi >> 4) & 3, ww = (wi >> 2) & 3, wt = wi & 3;
      const int aa = (n >> 6) & 3, bb = (n >> 4) & 3, cc = (n >> 2) & 3, dd = n & 3;
      const int sd = (wd * 4 + aa + 2) & 15, sh = (wh * 4 + bb + 2) & 15;
      const int sw = (ww * 4 + cc + 2) & 15, st = (wt * 4 + dd + 2) & 15;
      const size_t gg = ((((size_t)(batch * 16 + sd) * 16 + sh) * 16 + sw) * 16 + st);
      #pragma unroll
      for (int nt = 0; nt < 6; nt++) {
        int c = nt * 16 + l15;
        out[gg * 96 + c] = x[gg * 96 + c] + proj_b[c] + acc[m][nt][r];
      }
    }
  }
}

// ------- K2: MFMA fused MLP, 128 tok/block, reg weights, ZERO barriers -------
__global__ __launch_bounds__(256, 3) void k_mlp(
    float* __restrict__ io,
    const float* __restrict__ n2g, const float* __restrict__ n2b,
    const unsigned short* __restrict__ img,
    const float* __restrict__ fc1_b, const float* __restrict__ fc2_b) {
  __shared__ __align__(16) short s_a[128 * 104];   // LN2 out (wave-private rows)
  __shared__ __align__(16) short s_h[128 * 104];   // GELU out (wave-private rows)

  const int tid = threadIdx.x;
  const int w = tid >> 6, l = tid & 63;
  const int quad = l >> 4, l15 = l & 15;
  const size_t t0 = (size_t)blockIdx.x * 128;
  const f32x4 fz = {0.f, 0.f, 0.f, 0.f};

  // ---- LN2: 2 threads per token, 48 channels each ----
  {
    const int r = tid >> 1, hf = tid & 1;
    const float4* base = (const float4*)(io + (t0 + r) * 96 + hf * 48);
    float v[48];
    float s = 0.f, q = 0.f;
    #pragma unroll
    for (int j = 0; j < 12; j++) {
      float4 f = base[j];
      v[4 * j] = f.x; v[4 * j + 1] = f.y; v[4 * j + 2] = f.z; v[4 * j + 3] = f.w;
      s += f.x + f.y + f.z + f.w;
      q += f.x * f.x + f.y * f.y + f.z * f.z + f.w * f.w;
    }
    s += __shfl_xor(s, 1); q += __shfl_xor(q, 1);
    const float mu = s * (1.f / 96.f);
    const float var = q * (1.f / 96.f) - mu * mu;
    const float rs = rsqrtf(fmaxf(var, 0.f) + 1e-5f);
    unsigned int* row = (unsigned int*)&s_a[r * 104] + hf * 24;
    #pragma unroll
    for (int jj = 0; jj < 24; jj++) {
      int k0 = hf * 48 + 2 * jj;
      float lo = (v[2 * jj]     - mu) * rs * n2g[k0]     + n2b[k0];
      float hi = (v[2 * jj + 1] - mu) * rs * n2g[k0 + 1] + n2b[k0 + 1];
      row[jj] = cvtpk(lo, hi);
    }
  }
  // s_a rows [w*32, w*32+32) written and read by wave w only -> no barrier.

  f32x4 acc2[2][6];
  #pragma unroll
  for (int m = 0; m < 2; m++)
    #pragma unroll
    for (int i = 0; i < 6; i++) acc2[m][i] = fz;

  for (int nc = 0; nc < 4; nc++) {
    f32x4 acc1[2][6];
    #pragma unroll
    for (int m = 0; m < 2; m++)
      #pragma unroll
      for (int i = 0; i < 6; i++) acc1[m][i] = fz;
    #pragma unroll
    for (int ks = 0; ks < 3; ks++) {
      bf16x8 bw[6];
      #pragma unroll
      for (int nt = 0; nt < 6; nt++)
        bw[nt] = *(const bf16x8*)(img + IW1 + ((nc * 3 + ks) * 6 + nt) * 512 + l * 8);
      #pragma unroll
      for (int m = 0; m < 2; m++) {
        bf16x8 af = *(const bf16x8*)&s_a[(w * 32 + m * 16 + l15) * 104 + ks * 32 + quad * 8];
        #pragma unroll
        for (int nt = 0; nt < 6; nt++)
          acc1[m][nt] = __builtin_amdgcn_mfma_f32_16x16x32_bf16(af, bw[nt], acc1[m][nt], 0, 0, 0);
      }
    }
    // ---- GELU -> s_h (wave-private rows) ----
    #pragma unroll
    for (int m = 0; m < 2; m++)
      #pragma unroll
      for (int nt = 0; nt < 6; nt++) {
        int col = nt * 16 + l15;
        float bv = fc1_b[nc * 96 + col];
        #pragma unroll
        for (int r = 0; r < 4; r++) {
          float z = acc1[m][nt][r] + bv;
          float g = 0.5f * z * (1.f + erff(z * 0.70710678118654752f));
          s_h[(w * 32 + m * 16 + quad * 4 + r) * 104 + col] = (short)f2us(g);
        }
      }
    // ---- GEMM2 partial ----
    #pragma unroll
    for (int ks = 0; ks < 3; ks++) {
      bf16x8 bw[6];
      #pragma unroll
      for (int nt = 0; nt < 6; nt++)
        bw[nt] = *(const bf16x8*)(img + IW2 + ((nc * 3 + ks) * 6 + nt) * 512 + l * 8);
      #pragma unroll
      for (int m = 0; m < 2; m++) {
        bf16x8 af = *(const bf16x8*)&s_h[(w * 32 + m * 16 + l15) * 104 + ks * 32 + quad * 8];
        #pragma unroll
        for (int nt = 0; nt < 6; nt++)
          acc2[m][nt] = __builtin_amdgcn_mfma_f32_16x16x32_bf16(af, bw[nt], acc2[m][nt], 0, 0, 0);
      }
    }
  }

  #pragma unroll
  for (int m = 0; m < 2; m++)
    #pragma unroll
    for (int nt = 0; nt < 6; nt++) {
      int col = nt * 16 + l15;
      float bv = fc2_b[col];
      #pragma unroll
      for (int r = 0; r < 4; r++) {
        size_t idx = (t0 + w * 32 + m * 16 + quad * 4 + r) * 96 + col;
        io[idx] = io[idx] + acc2[m][nt][r] + bv;
      }
    }
}

extern "C" void kernel_launch(void* const* d_in, const int* in_sizes, int n_in,
                              void* d_out, int out_size, void* d_ws, size_t ws_size,
                              hipStream_t stream) {
  const float* x      = (const float*)d_in[0];
  const float* n1g    = (const float*)d_in[2];
  const float* n1b    = (const float*)d_in[3];
  const float* qkv_w  = (const float*)d_in[4];
  const float* qkv_b  = (const float*)d_in[5];
  const float* proj_w = (const float*)d_in[6];
  const float* proj_b = (const float*)d_in[7];
  const float* n2g    = (const float*)d_in[8];
  const float* n2b    = (const float*)d_in[9];
  const float* fc1_w  = (const float*)d_in[10];
  const float* fc1_b  = (const float*)d_in[11];
  const float* fc2_w  = (const float*)d_in[12];
  const float* fc2_b  = (const float*)d_in[13];
  float* out = (float*)d_out;

  // ws: xn bf16 (25,165,824 B) | img (227,328 B) | O bf16 (25,165,824 B)
  char* ws = (char*)d_ws;
  unsigned short* xn  = (unsigned short*)ws;
  unsigned short* img = (unsigned short*)(ws + 25165824u);
  unsigned short* og  = (unsigned short*)(ws + 25165824u + 227328u);

  k_prepw<<<IMG_SHORTS / 256, 256, 0, stream>>>(fc1_w, fc2_w, qkv_w, proj_w, img);
  k_ln1<<<TOK / 128, 256, 0, stream>>>(x, n1g, n1b, xn);
  k_win<<<BWIN, 256, 0, stream>>>(xn, img, qkv_b, og);
  k_proj<<<TOK / 128, 256, 0, stream>>>(og, x, img, proj_b, out);
  k_mlp<<<TOK / 128, 256, 0, stream>>>(out, n2g, n2b, img, fc1_b, fc2_b);
}

// Round 5
// 314.835 us; speedup vs baseline: 1.3534x; 1.3534x over previous
//
#include <hip/hip_runtime.h>

#define TOK   131072
#define BWIN  512

typedef __attribute__((ext_vector_type(8))) short bf16x8;
typedef __attribute__((ext_vector_type(4))) short bf16x4;
typedef __attribute__((ext_vector_type(4))) float f32x4;

__device__ __forceinline__ unsigned short f2us(float f) {   // RNE f32->bf16 bits
  union { float f; unsigned int i; } x; x.f = f;
  return (unsigned short)((x.i + 0x7fffu + ((x.i >> 16) & 1u)) >> 16);
}
__device__ __forceinline__ unsigned cvtpk(float lo, float hi) {  // 2xf32 -> packed bf16
  unsigned r;
  asm("v_cvt_pk_bf16_f32 %0, %1, %2" : "=v"(r) : "v"(lo), "v"(hi));
  return r;
}
union U8 { uint2 u; bf16x4 v; };

// ---- fragment-order bf16 weight images in ws (short offsets) ----
// Each fragment = 512 shorts (1 KB): lane l owns shorts [l*8, l*8+8).
// W1:   frag(nc,ks,nt) : fc1 B-operand  -> 4*3*6 = 72 frags
// W2:   frag(nc,ks,nt) : fc2 B-operand  -> 72 frags
// QKV:  frag(h,ks,mt)  : qkv A-operand  -> 4*3*5 = 60 frags (rows>=72 zero)
// PROJ: frag(ks,nt)    : proj B-operand, full K=96 -> 3*6 = 18 frags
#define IW1   0
#define IW2   36864
#define IQKV  73728
#define IPROJ 104448
#define IMG_SHORTS 113664

// ---------------- P0a: build fragment-order bf16 weight images ----------------
__global__ __launch_bounds__(256) void k_prepw(
    const float* __restrict__ fc1_w, const float* __restrict__ fc2_w,
    const float* __restrict__ qkv_w, const float* __restrict__ proj_w,
    unsigned short* __restrict__ img) {
  int i = blockIdx.x * 256 + threadIdx.x;    // 0..113663
  const int l = (i >> 3) & 63, j = i & 7;
  const int quad = l >> 4, l15 = l & 15;
  float v = 0.f;
  if (i < 36864) {                                        // W1 fragments
    int f = i >> 9; int nc = f / 18, rem = f - nc * 18;
    int ks = rem / 6, nt = rem - ks * 6;
    v = fc1_w[(size_t)(nc * 96 + nt * 16 + l15) * 96 + ks * 32 + quad * 8 + j];
  } else if (i < 73728) {                                 // W2 fragments
    int f = (i - 36864) >> 9; int nc = f / 18, rem = f - nc * 18;
    int ks = rem / 6, nt = rem - ks * 6;
    v = fc2_w[(size_t)(nt * 16 + l15) * 384 + nc * 96 + ks * 32 + quad * 8 + j];
  } else if (i < 104448) {                                // QKV A-fragments
    int f = (i - 73728) >> 9; int h = f / 15, rem = f - h * 15;
    int ks = rem / 5, mt = rem - ks * 5;
    int e = mt * 16 + l15;
    if (e < 72) {
      int grp = e / 24, rr = e - grp * 24;
      v = qkv_w[(size_t)(grp * 96 + h * 24 + rr) * 96 + ks * 32 + quad * 8 + j];
    }
  } else {                                                // proj B-fragments (full K)
    int f = (i - 104448) >> 9; int ks = f / 6, nt = f - ks * 6;
    v = proj_w[(size_t)(nt * 16 + l15) * 96 + ks * 32 + quad * 8 + j];
  }
  img[i] = f2us(v);
}

// ------- P0b: LN1 + cyclic shift -> xn bf16 (window order), 2 thr/token ------
__global__ __launch_bounds__(256) void k_ln1(const float* __restrict__ x,
                                             const float* __restrict__ g,
                                             const float* __restrict__ b,
                                             unsigned short* __restrict__ xn) {
  const int r = threadIdx.x >> 1, hf = threadIdx.x & 1;
  const int t = blockIdx.x * 128 + r;
  const int b_ = t >> 8, n = t & 255;
  const int batch = b_ >> 8, wi = b_ & 255;
  const int wd = (wi >> 6) & 3, wh = (wi >> 4) & 3, ww = (wi >> 2) & 3, wt = wi & 3;
  const int aa = (n >> 6) & 3, bb = (n >> 4) & 3, cc = (n >> 2) & 3, dd = n & 3;
  const int sd = (wd * 4 + aa + 2) & 15, sh = (wh * 4 + bb + 2) & 15;
  const int sw = (ww * 4 + cc + 2) & 15, st = (wt * 4 + dd + 2) & 15;
  const size_t gg = ((((size_t)(batch * 16 + sd) * 16 + sh) * 16 + sw) * 16 + st);

  const float4* base = (const float4*)(x + gg * 96 + hf * 48);
  float v[48];
  float s = 0.f, q2 = 0.f;
  #pragma unroll
  for (int j = 0; j < 12; j++) {
    float4 f = base[j];
    v[4 * j] = f.x; v[4 * j + 1] = f.y; v[4 * j + 2] = f.z; v[4 * j + 3] = f.w;
    s += f.x + f.y + f.z + f.w;
    q2 += f.x * f.x + f.y * f.y + f.z * f.z + f.w * f.w;
  }
  s += __shfl_xor(s, 1); q2 += __shfl_xor(q2, 1);
  const float mu = s * (1.f / 96.f);
  const float var = q2 * (1.f / 96.f) - mu * mu;
  const float rs = rsqrtf(fmaxf(var, 0.f) + 1e-5f);
  unsigned int* row = (unsigned int*)xn + (size_t)t * 48 + hf * 24;
  #pragma unroll
  for (int jj = 0; jj < 24; jj++) {
    int k0 = hf * 48 + 2 * jj;
    float a0 = (v[2 * jj]     - mu) * rs * g[k0]     + b[k0];
    float a1 = (v[2 * jj + 1] - mu) * rs * g[k0 + 1] + b[k0 + 1];
    row[jj] = cvtpk(a0, a1);
  }
}

// ---- k_win: QKV + attention only; O (normalized, bf16) -> global window-order
// LDS: s_k [256][36] + s_vt [32][260] + labels = 35,328 B
// launch_bounds(256,2): 256-reg combined budget -> no spill (R4's (256,4)
// halved it to 64 arch VGPRs and spilled ~300 MB to scratch).
__global__ __launch_bounds__(256, 2) void k_win(
    const unsigned short* __restrict__ xn,
    const unsigned short* __restrict__ img,
    const float* __restrict__ qkv_b,
    unsigned short* __restrict__ og) {
  __shared__ __align__(16) short s_k[256 * 36];    // K  [tok][36], e 24..31 zero
  __shared__ __align__(16) short s_vt[32 * 260];   // V^T [e][tok], rows 24..31 zero
  __shared__ unsigned char s_lb[256];

  const int tid = threadIdx.x;
  const int w = tid >> 6, l = tid & 63, quad = l >> 4, l15 = l & 15;
  const int q0 = w * 64;                       // wave's 64-token strip
  const int b_ = blockIdx.x;
  const int wi = b_ & 255;
  const int wd = (wi >> 6) & 3, wh = (wi >> 4) & 3, ww = (wi >> 2) & 3, wt = wi & 3;
  const float scale = 0.20412414523193154f;    // 24^-0.5
  const f32x4 fz = {0.f, 0.f, 0.f, 0.f};

  // ---- phase 0: labels + zero pads ----
  {
    const int n = tid;
    const int aa = (n >> 6) & 3, bb = (n >> 4) & 3, cc = (n >> 2) & 3, dd = n & 3;
    const int p0 = wd * 4 + aa, p1 = wh * 4 + bb, p2 = ww * 4 + cc, p3 = wt * 4 + dd;
    const int r0 = p0 >= 14 ? 2 : (p0 >= 12 ? 1 : 0);
    const int r1 = p1 >= 14 ? 2 : (p1 >= 12 ? 1 : 0);
    const int r2 = p2 >= 14 ? 2 : (p2 >= 12 ? 1 : 0);
    const int r3 = p3 >= 14 ? 2 : (p3 >= 12 ? 1 : 0);
    s_lb[n] = (unsigned char)(((r0 * 3 + r1) * 3 + r2) * 3 + r3);
    *(uint2*)&s_k[n * 36 + 24] = make_uint2(0u, 0u);   // e 24..27
    *(uint2*)&s_k[n * 36 + 28] = make_uint2(0u, 0u);   // e 28..31
    unsigned int* vz = (unsigned int*)(s_vt + 24 * 260);
    for (int i = tid; i < 8 * 130; i += 256) vz[i] = 0u;  // V rows 24..31 = 0
  }
  __syncthreads();

  const unsigned short* xw = xn + (size_t)b_ * 256 * 96;
  const unsigned short* wq = img + IQKV;

  for (int h = 0; h < 4; h++) {
    // ---- QKV GEMM (swapped, x32): weights direct global->reg fragments ----
    f32x4 acc[5][4];
    #pragma unroll
    for (int mt = 0; mt < 5; mt++)
      #pragma unroll
      for (int nt = 0; nt < 4; nt++) acc[mt][nt] = fz;
    #pragma unroll
    for (int ks = 0; ks < 3; ks++) {
      bf16x8 aw[5];
      #pragma unroll
      for (int mt = 0; mt < 5; mt++)
        aw[mt] = *(const bf16x8*)(wq + ((h * 3 + ks) * 5 + mt) * 512 + l * 8);
      #pragma unroll
      for (int nt = 0; nt < 4; nt++) {
        bf16x8 bx = *(const bf16x8*)(xw + (size_t)(q0 + nt * 16 + l15) * 96 + ks * 32 + quad * 8);
        #pragma unroll
        for (int mt = 0; mt < 5; mt++)
          acc[mt][nt] = __builtin_amdgcn_mfma_f32_16x16x32_bf16(aw[mt], bx, acc[mt][nt], 0, 0, 0);
      }
    }
    // ---- Q: pack in-register (B-operand of 16x16x16, e chunks mt=0,1) ----
    U8 qq[2][4];
    #pragma unroll
    for (int mt = 0; mt < 2; mt++) {
      const int e0 = mt * 16 + quad * 4;
      float b0 = qkv_b[h * 24 + e0],     b1 = qkv_b[h * 24 + e0 + 1];
      float b2 = qkv_b[h * 24 + e0 + 2], b3 = qkv_b[h * 24 + e0 + 3];
      #pragma unroll
      for (int nt = 0; nt < 4; nt++) {
        qq[mt][nt].u.x = cvtpk((acc[mt][nt][0] + b0) * scale, (acc[mt][nt][1] + b1) * scale);
        qq[mt][nt].u.y = cvtpk((acc[mt][nt][2] + b2) * scale, (acc[mt][nt][3] + b3) * scale);
      }
    }
    // ---- scatter K (uint2) / V^T (shorts) to LDS ----
    #pragma unroll
    for (int mt = 1; mt < 5; mt++) {
      const int e0 = mt * 16 + quad * 4;
      #pragma unroll
      for (int nt = 0; nt < 4; nt++) {
        const int tok = q0 + nt * 16 + l15;
        if (e0 >= 24 && e0 < 48) {       // K
          const int e = e0 - 24;
          uint2 pk;
          pk.x = cvtpk(acc[mt][nt][0] + qkv_b[96 + h * 24 + e],
                       acc[mt][nt][1] + qkv_b[96 + h * 24 + e + 1]);
          pk.y = cvtpk(acc[mt][nt][2] + qkv_b[96 + h * 24 + e + 2],
                       acc[mt][nt][3] + qkv_b[96 + h * 24 + e + 3]);
          *(uint2*)&s_k[tok * 36 + e] = pk;
        } else if (e0 >= 48 && e0 < 72) {  // V^T
          const int e = e0 - 48;
          #pragma unroll
          for (int r = 0; r < 4; r++)
            s_vt[(e + r) * 260 + tok] = (short)f2us(acc[mt][nt][r] + qkv_b[192 + h * 24 + e + r]);
        }
      }
    }
    __syncthreads();                                           // K/V visible
    // ---- attention: per 16-query tile, P and Q never touch LDS ----
    #pragma unroll 1
    for (int mt4 = 0; mt4 < 4; mt4++) {
      const int qt0 = q0 + mt4 * 16;
      f32x4 sc[16];
      #pragma unroll
      for (int km = 0; km < 16; km++) sc[km] = fz;
      const bf16x4 bq0 = qq[0][mt4].v, bq1 = qq[1][mt4].v;
      __builtin_amdgcn_s_setprio(1);
      #pragma unroll
      for (int km = 0; km < 16; km++) {
        bf16x4 ak0 = *(const bf16x4*)&s_k[(km * 16 + l15) * 36 + quad * 4];
        bf16x4 ak1 = *(const bf16x4*)&s_k[(km * 16 + l15) * 36 + 16 + quad * 4];
        sc[km] = __builtin_amdgcn_mfma_f32_16x16x16bf16_1k(ak0, bq0, sc[km], 0, 0, 0);
        sc[km] = __builtin_amdgcn_mfma_f32_16x16x16bf16_1k(ak1, bq1, sc[km], 0, 0, 0);
      }
      __builtin_amdgcn_s_setprio(0);
      // ---- masked exp (in place) + in-register row-sum ----
      const unsigned lq = s_lb[qt0 + l15];
      float rsum = 0.f;
      #pragma unroll
      for (int km = 0; km < 16; km++) {
        unsigned lj = *(const unsigned*)&s_lb[km * 16 + quad * 4];
        float p0 = ((lj & 255u)         == lq) ? __expf(sc[km][0]) : 0.f;
        float p1 = (((lj >> 8) & 255u)  == lq) ? __expf(sc[km][1]) : 0.f;
        float p2 = (((lj >> 16) & 255u) == lq) ? __expf(sc[km][2]) : 0.f;
        float p3 = ((lj >> 24)          == lq) ? __expf(sc[km][3]) : 0.f;
        sc[km][0] = p0; sc[km][1] = p1; sc[km][2] = p2; sc[km][3] = p3;
        rsum += (p0 + p1) + (p2 + p3);
      }
      rsum += __shfl_xor(rsum, 16, 64);
      rsum += __shfl_xor(rsum, 32, 64);
      const float inv = 1.f / rsum;
      // ---- PV (x16): P fed straight from registers ----
      f32x4 ov0 = fz, ov1 = fz;
      __builtin_amdgcn_s_setprio(1);
      #pragma unroll
      for (int km = 0; km < 16; km++) {
        U8 bp;
        bp.u.x = cvtpk(sc[km][0], sc[km][1]);
        bp.u.y = cvtpk(sc[km][2], sc[km][3]);
        bf16x4 av0 = *(const bf16x4*)&s_vt[l15 * 260 + km * 16 + quad * 4];
        bf16x4 av1 = *(const bf16x4*)&s_vt[(16 + l15) * 260 + km * 16 + quad * 4];
        ov0 = __builtin_amdgcn_mfma_f32_16x16x16bf16_1k(av0, bp.v, ov0, 0, 0, 0);
        ov1 = __builtin_amdgcn_mfma_f32_16x16x16bf16_1k(av1, bp.v, ov1, 0, 0, 0);
      }
      __builtin_amdgcn_s_setprio(0);
      // ---- O (normalized, bf16) straight to global, window order ----
      uint2 o0, o1;
      o0.x = cvtpk(ov0[0] * inv, ov0[1] * inv);
      o0.y = cvtpk(ov0[2] * inv, ov0[3] * inv);
      o1.x = cvtpk(ov1[0] * inv, ov1[1] * inv);
      o1.y = cvtpk(ov1[2] * inv, ov1[3] * inv);
      size_t ob = ((size_t)b_ * 256 + qt0 + l15) * 96 + h * 24;
      *(uint2*)&og[ob + quad * 4] = o0;                  // e 0..15
      if (quad < 2) *(uint2*)&og[ob + 16 + quad * 4] = o1;  // e 16..23
    }
    __syncthreads();               // all waves done with s_k/s_vt for this head
  }
}

// ---- k_proj: out = x + O @ Wp^T + pb  (O window-order bf16, out spatial f32)
__global__ __launch_bounds__(256, 2) void k_proj(
    const unsigned short* __restrict__ og, const float* __restrict__ x,
    const unsigned short* __restrict__ img,
    const float* __restrict__ proj_b, float* __restrict__ out) {
  const int tid = threadIdx.x;
  const int w = tid >> 6, l = tid & 63, quad = l >> 4, l15 = l & 15;
  const int t0 = blockIdx.x * 128;
  const f32x4 fz = {0.f, 0.f, 0.f, 0.f};

  f32x4 acc[2][6];
  #pragma unroll
  for (int m = 0; m < 2; m++)
    #pragma unroll
    for (int nt = 0; nt < 6; nt++) acc[m][nt] = fz;

  #pragma unroll
  for (int ks = 0; ks < 3; ks++) {
    bf16x8 bw[6];
    #pragma unroll
    for (int nt = 0; nt < 6; nt++)
      bw[nt] = *(const bf16x8*)(img + IPROJ + (ks * 6 + nt) * 512 + l * 8);
    #pragma unroll
    for (int m = 0; m < 2; m++) {
      bf16x8 af = *(const bf16x8*)(og + (size_t)(t0 + w * 32 + m * 16 + l15) * 96 + ks * 32 + quad * 8);
      #pragma unroll
      for (int nt = 0; nt < 6; nt++)
        acc[m][nt] = __builtin_amdgcn_mfma_f32_16x16x32_bf16(af, bw[nt], acc[m][nt], 0, 0, 0);
    }
  }

  // ---- epilogue: window token -> spatial address; bias + residual ----
  #pragma unroll
  for (int m = 0; m < 2; m++) {
    #pragma unroll
    for (int r = 0; r < 4; r++) {
      const int T = t0 + w * 32 + m * 16 + quad * 4 + r;
      const int b_ = T >> 8, n = T & 255;
      const int batch = b_ >> 8, wi = b_ & 255;
      const int wd = (wi >> 6) & 3, wh = (wi >> 4) & 3, ww = (wi >> 2) & 3, wt = wi & 3;
      const int aa = (n >> 6) & 3, bb = (n >> 4) & 3, cc = (n >> 2) & 3, dd = n & 3;
      const int sd = (wd * 4 + aa + 2) & 15, sh = (wh * 4 + bb + 2) & 15;
      const int sw = (ww * 4 + cc + 2) & 15, st = (wt * 4 + dd + 2) & 15;
      const size_t gg = ((((size_t)(batch * 16 + sd) * 16 + sh) * 16 + sw) * 16 + st);
      #pragma unroll
      for (int nt = 0; nt < 6; nt++) {
        int c = nt * 16 + l15;
        out[gg * 96 + c] = x[gg * 96 + c] + proj_b[c] + acc[m][nt][r];
      }
    }
  }
}

// ------- K2: MFMA fused MLP, 128 tok/block, reg weights, ZERO barriers -------
__global__ __launch_bounds__(256, 3) void k_mlp(
    float* __restrict__ io,
    const float* __restrict__ n2g, const float* __restrict__ n2b,
    const unsigned short* __restrict__ img,
    const float* __restrict__ fc1_b, const float* __restrict__ fc2_b) {
  __shared__ __align__(16) short s_a[128 * 104];   // LN2 out (wave-private rows)
  __shared__ __align__(16) short s_h[128 * 104];   // GELU out (wave-private rows)

  const int tid = threadIdx.x;
  const int w = tid >> 6, l = tid & 63;
  const int quad = l >> 4, l15 = l & 15;
  const size_t t0 = (size_t)blockIdx.x * 128;
  const f32x4 fz = {0.f, 0.f, 0.f, 0.f};

  // ---- LN2: 2 threads per token, 48 channels each ----
  {
    const int r = tid >> 1, hf = tid & 1;
    const float4* base = (const float4*)(io + (t0 + r) * 96 + hf * 48);
    float v[48];
    float s = 0.f, q = 0.f;
    #pragma unroll
    for (int j = 0; j < 12; j++) {
      float4 f = base[j];
      v[4 * j] = f.x; v[4 * j + 1] = f.y; v[4 * j + 2] = f.z; v[4 * j + 3] = f.w;
      s += f.x + f.y + f.z + f.w;
      q += f.x * f.x + f.y * f.y + f.z * f.z + f.w * f.w;
    }
    s += __shfl_xor(s, 1); q += __shfl_xor(q, 1);
    const float mu = s * (1.f / 96.f);
    const float var = q * (1.f / 96.f) - mu * mu;
    const float rs = rsqrtf(fmaxf(var, 0.f) + 1e-5f);
    unsigned int* row = (unsigned int*)&s_a[r * 104] + hf * 24;
    #pragma unroll
    for (int jj = 0; jj < 24; jj++) {
      int k0 = hf * 48 + 2 * jj;
      float lo = (v[2 * jj]     - mu) * rs * n2g[k0]     + n2b[k0];
      float hi = (v[2 * jj + 1] - mu) * rs * n2g[k0 + 1] + n2b[k0 + 1];
      row[jj] = cvtpk(lo, hi);
    }
  }
  // s_a rows [w*32, w*32+32) written and read by wave w only -> no barrier.

  f32x4 acc2[2][6];
  #pragma unroll
  for (int m = 0; m < 2; m++)
    #pragma unroll
    for (int i = 0; i < 6; i++) acc2[m][i] = fz;

  for (int nc = 0; nc < 4; nc++) {
    f32x4 acc1[2][6];
    #pragma unroll
    for (int m = 0; m < 2; m++)
      #pragma unroll
      for (int i = 0; i < 6; i++) acc1[m][i] = fz;
    #pragma unroll
    for (int ks = 0; ks < 3; ks++) {
      bf16x8 bw[6];
      #pragma unroll
      for (int nt = 0; nt < 6; nt++)
        bw[nt] = *(const bf16x8*)(img + IW1 + ((nc * 3 + ks) * 6 + nt) * 512 + l * 8);
      #pragma unroll
      for (int m = 0; m < 2; m++) {
        bf16x8 af = *(const bf16x8*)&s_a[(w * 32 + m * 16 + l15) * 104 + ks * 32 + quad * 8];
        #pragma unroll
        for (int nt = 0; nt < 6; nt++)
          acc1[m][nt] = __builtin_amdgcn_mfma_f32_16x16x32_bf16(af, bw[nt], acc1[m][nt], 0, 0, 0);
      }
    }
    // ---- GELU -> s_h (wave-private rows) ----
    #pragma unroll
    for (int m = 0; m < 2; m++)
      #pragma unroll
      for (int nt = 0; nt < 6; nt++) {
        int col = nt * 16 + l15;
        float bv = fc1_b[nc * 96 + col];
        #pragma unroll
        for (int r = 0; r < 4; r++) {
          float z = acc1[m][nt][r] + bv;
          float g = 0.5f * z * (1.f + erff(z * 0.70710678118654752f));
          s_h[(w * 32 + m * 16 + quad * 4 + r) * 104 + col] = (short)f2us(g);
        }
      }
    // ---- GEMM2 partial ----
    #pragma unroll
    for (int ks = 0; ks < 3; ks++) {
      bf16x8 bw[6];
      #pragma unroll
      for (int nt = 0; nt < 6; nt++)
        bw[nt] = *(const bf16x8*)(img + IW2 + ((nc * 3 + ks) * 6 + nt) * 512 + l * 8);
      #pragma unroll
      for (int m = 0; m < 2; m++) {
        bf16x8 af = *(const bf16x8*)&s_h[(w * 32 + m * 16 + l15) * 104 + ks * 32 + quad * 8];
        #pragma unroll
        for (int nt = 0; nt < 6; nt++)
          acc2[m][nt] = __builtin_amdgcn_mfma_f32_16x16x32_bf16(af, bw[nt], acc2[m][nt], 0, 0, 0);
      }
    }
  }

  #pragma unroll
  for (int m = 0; m < 2; m++)
    #pragma unroll
    for (int nt = 0; nt < 6; nt++) {
      int col = nt * 16 + l15;
      float bv = fc2_b[col];
      #pragma unroll
      for (int r = 0; r < 4; r++) {
        size_t idx = (t0 + w * 32 + m * 16 + quad * 4 + r) * 96 + col;
        io[idx] = io[idx] + acc2[m][nt][r] + bv;
      }
    }
}

extern "C" void kernel_launch(void* const* d_in, const int* in_sizes, int n_in,
                              void* d_out, int out_size, void* d_ws, size_t ws_size,
                              hipStream_t stream) {
  const float* x      = (const float*)d_in[0];
  const float* n1g    = (const float*)d_in[2];
  const float* n1b    = (const float*)d_in[3];
  const float* qkv_w  = (const float*)d_in[4];
  const float* qkv_b  = (const float*)d_in[5];
  const float* proj_w = (const float*)d_in[6];
  const float* proj_b = (const float*)d_in[7];
  const float* n2g    = (const float*)d_in[8];
  const float* n2b    = (const float*)d_in[9];
  const float* fc1_w  = (const float*)d_in[10];
  const float* fc1_b  = (const float*)d_in[11];
  const float* fc2_w  = (const float*)d_in[12];
  const float* fc2_b  = (const float*)d_in[13];
  float* out = (float*)d_out;

  // ws: xn bf16 (25,165,824 B) | img (227,328 B) | O bf16 (25,165,824 B)
  char* ws = (char*)d_ws;
  unsigned short* xn  = (unsigned short*)ws;
  unsigned short* img = (unsigned short*)(ws + 25165824u);
  unsigned short* og  = (unsigned short*)(ws + 25165824u + 227328u);

  k_prepw<<<IMG_SHORTS / 256, 256, 0, stream>>>(fc1_w, fc2_w, qkv_w, proj_w, img);
  k_ln1<<<TOK / 128, 256, 0, stream>>>(x, n1g, n1b, xn);
  k_win<<<BWIN, 256, 0, stream>>>(xn, img, qkv_b, og);
  k_proj<<<TOK / 128, 256, 0, stream>>>(og, x, img, proj_b, out);
  k_mlp<<<TOK / 128, 256, 0, stream>>>(out, n2g, n2b, img, fc1_b, fc2_b);
}

// Round 6
// 299.330 us; speedup vs baseline: 1.4235x; 1.0518x over previous
//
#include <hip/hip_runtime.h>

#define TOK   131072
#define BWIN  512

typedef __attribute__((ext_vector_type(8))) short bf16x8;
typedef __attribute__((ext_vector_type(4))) short bf16x4;
typedef __attribute__((ext_vector_type(4))) float f32x4;

__device__ __forceinline__ unsigned short f2us(float f) {   // RNE f32->bf16 bits
  union { float f; unsigned int i; } x; x.f = f;
  return (unsigned short)((x.i + 0x7fffu + ((x.i >> 16) & 1u)) >> 16);
}
__device__ __forceinline__ unsigned cvtpk(float lo, float hi) {  // 2xf32 -> packed bf16
  unsigned r;
  asm("v_cvt_pk_bf16_f32 %0, %1, %2" : "=v"(r) : "v"(lo), "v"(hi));
  return r;
}
union U8 { uint2 u; bf16x4 v; };

// ---- fragment-order bf16 weight images in ws (short offsets) ----
// Each fragment = 512 shorts (1 KB): lane l owns shorts [l*8, l*8+8).
// W1:   frag(nc,ks,nt) : fc1 B-operand  -> 4*3*6 = 72 frags
// W2:   frag(nc,ks,nt) : fc2 B-operand  -> 72 frags
// QKV:  frag(h,ks,mt)  : qkv A-operand  -> 4*3*5 = 60 frags (rows>=72 zero)
// PROJ: frag(ks,nt)    : proj B-operand, full K=96 -> 3*6 = 18 frags
#define IW1   0
#define IW2   36864
#define IQKV  73728
#define IPROJ 104448
#define IMG_SHORTS 113664

// ---------------- P0a: build fragment-order bf16 weight images ----------------
__global__ __launch_bounds__(256) void k_prepw(
    const float* __restrict__ fc1_w, const float* __restrict__ fc2_w,
    const float* __restrict__ qkv_w, const float* __restrict__ proj_w,
    unsigned short* __restrict__ img) {
  int i = blockIdx.x * 256 + threadIdx.x;    // 0..113663
  const int l = (i >> 3) & 63, j = i & 7;
  const int quad = l >> 4, l15 = l & 15;
  float v = 0.f;
  if (i < 36864) {                                        // W1 fragments
    int f = i >> 9; int nc = f / 18, rem = f - nc * 18;
    int ks = rem / 6, nt = rem - ks * 6;
    v = fc1_w[(size_t)(nc * 96 + nt * 16 + l15) * 96 + ks * 32 + quad * 8 + j];
  } else if (i < 73728) {                                 // W2 fragments
    int f = (i - 36864) >> 9; int nc = f / 18, rem = f - nc * 18;
    int ks = rem / 6, nt = rem - ks * 6;
    v = fc2_w[(size_t)(nt * 16 + l15) * 384 + nc * 96 + ks * 32 + quad * 8 + j];
  } else if (i < 104448) {                                // QKV A-fragments
    int f = (i - 73728) >> 9; int h = f / 15, rem = f - h * 15;
    int ks = rem / 5, mt = rem - ks * 5;
    int e = mt * 16 + l15;
    if (e < 72) {
      int grp = e / 24, rr = e - grp * 24;
      v = qkv_w[(size_t)(grp * 96 + h * 24 + rr) * 96 + ks * 32 + quad * 8 + j];
    }
  } else {                                                // proj B-fragments (full K)
    int f = (i - 104448) >> 9; int ks = f / 6, nt = f - ks * 6;
    v = proj_w[(size_t)(nt * 16 + l15) * 96 + ks * 32 + quad * 8 + j];
  }
  img[i] = f2us(v);
}

// ------- P0b: LN1 + cyclic shift -> xn bf16 (window order), 2 thr/token ------
__global__ __launch_bounds__(256) void k_ln1(const float* __restrict__ x,
                                             const float* __restrict__ g,
                                             const float* __restrict__ b,
                                             unsigned short* __restrict__ xn) {
  const int r = threadIdx.x >> 1, hf = threadIdx.x & 1;
  const int t = blockIdx.x * 128 + r;
  const int b_ = t >> 8, n = t & 255;
  const int batch = b_ >> 8, wi = b_ & 255;
  const int wd = (wi >> 6) & 3, wh = (wi >> 4) & 3, ww = (wi >> 2) & 3, wt = wi & 3;
  const int aa = (n >> 6) & 3, bb = (n >> 4) & 3, cc = (n >> 2) & 3, dd = n & 3;
  const int sd = (wd * 4 + aa + 2) & 15, sh = (wh * 4 + bb + 2) & 15;
  const int sw = (ww * 4 + cc + 2) & 15, st = (wt * 4 + dd + 2) & 15;
  const size_t gg = ((((size_t)(batch * 16 + sd) * 16 + sh) * 16 + sw) * 16 + st);

  const float4* base = (const float4*)(x + gg * 96 + hf * 48);
  float v[48];
  float s = 0.f, q2 = 0.f;
  #pragma unroll
  for (int j = 0; j < 12; j++) {
    float4 f = base[j];
    v[4 * j] = f.x; v[4 * j + 1] = f.y; v[4 * j + 2] = f.z; v[4 * j + 3] = f.w;
    s += f.x + f.y + f.z + f.w;
    q2 += f.x * f.x + f.y * f.y + f.z * f.z + f.w * f.w;
  }
  s += __shfl_xor(s, 1); q2 += __shfl_xor(q2, 1);
  const float mu = s * (1.f / 96.f);
  const float var = q2 * (1.f / 96.f) - mu * mu;
  const float rs = rsqrtf(fmaxf(var, 0.f) + 1e-5f);
  unsigned int* row = (unsigned int*)xn + (size_t)t * 48 + hf * 24;
  #pragma unroll
  for (int jj = 0; jj < 24; jj++) {
    int k0 = hf * 48 + 2 * jj;
    float a0 = (v[2 * jj]     - mu) * rs * g[k0]     + b[k0];
    float a1 = (v[2 * jj + 1] - mu) * rs * g[k0 + 1] + b[k0 + 1];
    row[jj] = cvtpk(a0, a1);
  }
}

// ---- k_win: QKV + attention only; O (normalized, bf16) -> global window-order
// LDS: s_k [256][36] + s_vt [32][260] + labels = 35,328 B
// launch_bounds(256,2): 256-reg combined budget -> no spill (R4's (256,4)
// halved it to 64 arch VGPRs and spilled ~300 MB to scratch).
__global__ __launch_bounds__(256, 2) void k_win(
    const unsigned short* __restrict__ xn,
    const unsigned short* __restrict__ img,
    const float* __restrict__ qkv_b,
    unsigned short* __restrict__ og) {
  __shared__ __align__(16) short s_k[256 * 36];    // K  [tok][36], e 24..31 zero
  __shared__ __align__(16) short s_vt[32 * 260];   // V^T [e][tok], rows 24..31 zero
  __shared__ unsigned char s_lb[256];

  const int tid = threadIdx.x;
  const int w = tid >> 6, l = tid & 63, quad = l >> 4, l15 = l & 15;
  const int q0 = w * 64;                       // wave's 64-token strip
  const int b_ = blockIdx.x;
  const int wi = b_ & 255;
  const int wd = (wi >> 6) & 3, wh = (wi >> 4) & 3, ww = (wi >> 2) & 3, wt = wi & 3;
  const float scale = 0.20412414523193154f;    // 24^-0.5
  const f32x4 fz = {0.f, 0.f, 0.f, 0.f};

  // ---- phase 0: labels + zero pads ----
  {
    const int n = tid;
    const int aa = (n >> 6) & 3, bb = (n >> 4) & 3, cc = (n >> 2) & 3, dd = n & 3;
    const int p0 = wd * 4 + aa, p1 = wh * 4 + bb, p2 = ww * 4 + cc, p3 = wt * 4 + dd;
    const int r0 = p0 >= 14 ? 2 : (p0 >= 12 ? 1 : 0);
    const int r1 = p1 >= 14 ? 2 : (p1 >= 12 ? 1 : 0);
    const int r2 = p2 >= 14 ? 2 : (p2 >= 12 ? 1 : 0);
    const int r3 = p3 >= 14 ? 2 : (p3 >= 12 ? 1 : 0);
    s_lb[n] = (unsigned char)(((r0 * 3 + r1) * 3 + r2) * 3 + r3);
    *(uint2*)&s_k[n * 36 + 24] = make_uint2(0u, 0u);   // e 24..27
    *(uint2*)&s_k[n * 36 + 28] = make_uint2(0u, 0u);   // e 28..31
    unsigned int* vz = (unsigned int*)(s_vt + 24 * 260);
    for (int i = tid; i < 8 * 130; i += 256) vz[i] = 0u;  // V rows 24..31 = 0
  }
  __syncthreads();

  const unsigned short* xw = xn + (size_t)b_ * 256 * 96;
  const unsigned short* wq = img + IQKV;

  for (int h = 0; h < 4; h++) {
    // ---- QKV GEMM (swapped, x32): weights direct global->reg fragments ----
    f32x4 acc[5][4];
    #pragma unroll
    for (int mt = 0; mt < 5; mt++)
      #pragma unroll
      for (int nt = 0; nt < 4; nt++) acc[mt][nt] = fz;
    #pragma unroll
    for (int ks = 0; ks < 3; ks++) {
      bf16x8 aw[5];
      #pragma unroll
      for (int mt = 0; mt < 5; mt++)
        aw[mt] = *(const bf16x8*)(wq + ((h * 3 + ks) * 5 + mt) * 512 + l * 8);
      #pragma unroll
      for (int nt = 0; nt < 4; nt++) {
        bf16x8 bx = *(const bf16x8*)(xw + (size_t)(q0 + nt * 16 + l15) * 96 + ks * 32 + quad * 8);
        #pragma unroll
        for (int mt = 0; mt < 5; mt++)
          acc[mt][nt] = __builtin_amdgcn_mfma_f32_16x16x32_bf16(aw[mt], bx, acc[mt][nt], 0, 0, 0);
      }
    }
    // ---- Q: pack in-register (B-operand of 16x16x16, e chunks mt=0,1) ----
    U8 qq[2][4];
    #pragma unroll
    for (int mt = 0; mt < 2; mt++) {
      const int e0 = mt * 16 + quad * 4;
      float b0 = qkv_b[h * 24 + e0],     b1 = qkv_b[h * 24 + e0 + 1];
      float b2 = qkv_b[h * 24 + e0 + 2], b3 = qkv_b[h * 24 + e0 + 3];
      #pragma unroll
      for (int nt = 0; nt < 4; nt++) {
        qq[mt][nt].u.x = cvtpk((acc[mt][nt][0] + b0) * scale, (acc[mt][nt][1] + b1) * scale);
        qq[mt][nt].u.y = cvtpk((acc[mt][nt][2] + b2) * scale, (acc[mt][nt][3] + b3) * scale);
      }
    }
    // ---- scatter K (uint2) / V^T (shorts) to LDS ----
    #pragma unroll
    for (int mt = 1; mt < 5; mt++) {
      const int e0 = mt * 16 + quad * 4;
      #pragma unroll
      for (int nt = 0; nt < 4; nt++) {
        const int tok = q0 + nt * 16 + l15;
        if (e0 >= 24 && e0 < 48) {       // K
          const int e = e0 - 24;
          uint2 pk;
          pk.x = cvtpk(acc[mt][nt][0] + qkv_b[96 + h * 24 + e],
                       acc[mt][nt][1] + qkv_b[96 + h * 24 + e + 1]);
          pk.y = cvtpk(acc[mt][nt][2] + qkv_b[96 + h * 24 + e + 2],
                       acc[mt][nt][3] + qkv_b[96 + h * 24 + e + 3]);
          *(uint2*)&s_k[tok * 36 + e] = pk;
        } else if (e0 >= 48 && e0 < 72) {  // V^T
          const int e = e0 - 48;
          #pragma unroll
          for (int r = 0; r < 4; r++)
            s_vt[(e + r) * 260 + tok] = (short)f2us(acc[mt][nt][r] + qkv_b[192 + h * 24 + e + r]);
        }
      }
    }
    __syncthreads();                                           // K/V visible
    // ---- attention: per 16-query tile, P and Q never touch LDS ----
    #pragma unroll 1
    for (int mt4 = 0; mt4 < 4; mt4++) {
      const int qt0 = q0 + mt4 * 16;
      f32x4 sc[16];
      #pragma unroll
      for (int km = 0; km < 16; km++) sc[km] = fz;
      const bf16x4 bq0 = qq[0][mt4].v, bq1 = qq[1][mt4].v;
      __builtin_amdgcn_s_setprio(1);
      #pragma unroll
      for (int km = 0; km < 16; km++) {
        bf16x4 ak0 = *(const bf16x4*)&s_k[(km * 16 + l15) * 36 + quad * 4];
        bf16x4 ak1 = *(const bf16x4*)&s_k[(km * 16 + l15) * 36 + 16 + quad * 4];
        sc[km] = __builtin_amdgcn_mfma_f32_16x16x16bf16_1k(ak0, bq0, sc[km], 0, 0, 0);
        sc[km] = __builtin_amdgcn_mfma_f32_16x16x16bf16_1k(ak1, bq1, sc[km], 0, 0, 0);
      }
      __builtin_amdgcn_s_setprio(0);
      // ---- masked exp (in place) + in-register row-sum ----
      const unsigned lq = s_lb[qt0 + l15];
      float rsum = 0.f;
      #pragma unroll
      for (int km = 0; km < 16; km++) {
        unsigned lj = *(const unsigned*)&s_lb[km * 16 + quad * 4];
        float p0 = ((lj & 255u)         == lq) ? __expf(sc[km][0]) : 0.f;
        float p1 = (((lj >> 8) & 255u)  == lq) ? __expf(sc[km][1]) : 0.f;
        float p2 = (((lj >> 16) & 255u) == lq) ? __expf(sc[km][2]) : 0.f;
        float p3 = ((lj >> 24)          == lq) ? __expf(sc[km][3]) : 0.f;
        sc[km][0] = p0; sc[km][1] = p1; sc[km][2] = p2; sc[km][3] = p3;
        rsum += (p0 + p1) + (p2 + p3);
      }
      rsum += __shfl_xor(rsum, 16, 64);
      rsum += __shfl_xor(rsum, 32, 64);
      const float inv = 1.f / rsum;
      // ---- PV (x16): P fed straight from registers ----
      f32x4 ov0 = fz, ov1 = fz;
      __builtin_amdgcn_s_setprio(1);
      #pragma unroll
      for (int km = 0; km < 16; km++) {
        U8 bp;
        bp.u.x = cvtpk(sc[km][0], sc[km][1]);
        bp.u.y = cvtpk(sc[km][2], sc[km][3]);
        bf16x4 av0 = *(const bf16x4*)&s_vt[l15 * 260 + km * 16 + quad * 4];
        bf16x4 av1 = *(const bf16x4*)&s_vt[(16 + l15) * 260 + km * 16 + quad * 4];
        ov0 = __builtin_amdgcn_mfma_f32_16x16x16bf16_1k(av0, bp.v, ov0, 0, 0, 0);
        ov1 = __builtin_amdgcn_mfma_f32_16x16x16bf16_1k(av1, bp.v, ov1, 0, 0, 0);
      }
      __builtin_amdgcn_s_setprio(0);
      // ---- O (normalized, bf16) straight to global, window order ----
      uint2 o0, o1;
      o0.x = cvtpk(ov0[0] * inv, ov0[1] * inv);
      o0.y = cvtpk(ov0[2] * inv, ov0[3] * inv);
      o1.x = cvtpk(ov1[0] * inv, ov1[1] * inv);
      o1.y = cvtpk(ov1[2] * inv, ov1[3] * inv);
      size_t ob = ((size_t)b_ * 256 + qt0 + l15) * 96 + h * 24;
      *(uint2*)&og[ob + quad * 4] = o0;                  // e 0..15
      if (quad < 2) *(uint2*)&og[ob + 16 + quad * 4] = o1;  // e 16..23
    }
    __syncthreads();               // all waves done with s_k/s_vt for this head
  }
}

// ---- k_pm: fused proj + residual + LN2 + MLP + residual -> out --------------
// proj C-layout: token = t0+w*32+m*16+quad*4+r owned by 16 lanes (l15 varies),
// channel = nt*16+l15. LN2 stats via 4-step shfl_xor tree over the l15 group.
// s_a/s_h rows are wave-private -> ZERO barriers.
__global__ __launch_bounds__(256, 2) void k_pm(
    const unsigned short* __restrict__ og, const float* __restrict__ x,
    const unsigned short* __restrict__ img,
    const float* __restrict__ proj_b,
    const float* __restrict__ n2g, const float* __restrict__ n2b,
    const float* __restrict__ fc1_b, const float* __restrict__ fc2_b,
    float* __restrict__ out) {
  __shared__ __align__(16) short s_a[128 * 104];   // LN2 out (wave-private rows)
  __shared__ __align__(16) short s_h[128 * 104];   // GELU out (wave-private rows)

  const int tid = threadIdx.x;
  const int w = tid >> 6, l = tid & 63, quad = l >> 4, l15 = l & 15;
  const int t0 = blockIdx.x * 128;
  const f32x4 fz = {0.f, 0.f, 0.f, 0.f};

  // ---- per-lane channel constants (c = nt*16 + l15) ----
  float gn[6], bn[6], pb[6], f2[6];
  #pragma unroll
  for (int nt = 0; nt < 6; nt++) {
    int c = nt * 16 + l15;
    gn[nt] = n2g[c]; bn[nt] = n2b[c]; pb[nt] = proj_b[c]; f2[nt] = fc2_b[c];
  }

  // ---- phase 1: proj GEMM ----
  f32x4 pacc[2][6];
  #pragma unroll
  for (int m = 0; m < 2; m++)
    #pragma unroll
    for (int nt = 0; nt < 6; nt++) pacc[m][nt] = fz;
  #pragma unroll
  for (int ks = 0; ks < 3; ks++) {
    bf16x8 bw[6];
    #pragma unroll
    for (int nt = 0; nt < 6; nt++)
      bw[nt] = *(const bf16x8*)(img + IPROJ + (ks * 6 + nt) * 512 + l * 8);
    #pragma unroll
    for (int m = 0; m < 2; m++) {
      bf16x8 af = *(const bf16x8*)(og + (size_t)(t0 + w * 32 + m * 16 + l15) * 96 + ks * 32 + quad * 8);
      #pragma unroll
      for (int nt = 0; nt < 6; nt++)
        pacc[m][nt] = __builtin_amdgcn_mfma_f32_16x16x32_bf16(af, bw[nt], pacc[m][nt], 0, 0, 0);
    }
  }

  // ---- phase 2: residual x2 (regs) + LN2 stats (shfl tree) -> s_a bf16 ----
  float x2[2][6][4];
  size_t gg[2][4];
  #pragma unroll
  for (int m = 0; m < 2; m++) {
    #pragma unroll
    for (int r = 0; r < 4; r++) {
      const int T = t0 + w * 32 + m * 16 + quad * 4 + r;
      const int b_ = T >> 8, n = T & 255;
      const int batch = b_ >> 8, wi = b_ & 255;
      const int wd = (wi >> 6) & 3, wh = (wi >> 4) & 3, ww = (wi >> 2) & 3, wt = wi & 3;
      const int aa = (n >> 6) & 3, bb = (n >> 4) & 3, cc = (n >> 2) & 3, dd = n & 3;
      const int sd = (wd * 4 + aa + 2) & 15, sh = (wh * 4 + bb + 2) & 15;
      const int sw = (ww * 4 + cc + 2) & 15, st = (wt * 4 + dd + 2) & 15;
      gg[m][r] = ((((size_t)(batch * 16 + sd) * 16 + sh) * 16 + sw) * 16 + st);
      float s = 0.f, q = 0.f;
      #pragma unroll
      for (int nt = 0; nt < 6; nt++) {
        float v = x[gg[m][r] * 96 + nt * 16 + l15] + pb[nt] + pacc[m][nt][r];
        x2[m][nt][r] = v;
        s += v; q += v * v;
      }
      s += __shfl_xor(s, 1); q += __shfl_xor(q, 1);
      s += __shfl_xor(s, 2); q += __shfl_xor(q, 2);
      s += __shfl_xor(s, 4); q += __shfl_xor(q, 4);
      s += __shfl_xor(s, 8); q += __shfl_xor(q, 8);
      const float mu = s * (1.f / 96.f);
      const float var = q * (1.f / 96.f) - mu * mu;
      const float rs = rsqrtf(fmaxf(var, 0.f) + 1e-5f);
      const int tr = w * 32 + m * 16 + quad * 4 + r;
      #pragma unroll
      for (int nt = 0; nt < 6; nt++)
        s_a[tr * 104 + nt * 16 + l15] =
            (short)f2us((x2[m][nt][r] - mu) * rs * gn[nt] + bn[nt]);
    }
  }
  // s_a rows [w*32, w*32+32) written and read by wave w only -> no barrier.

  // ---- phase 3: MLP ----
  f32x4 acc2[2][6];
  #pragma unroll
  for (int m = 0; m < 2; m++)
    #pragma unroll
    for (int i = 0; i < 6; i++) acc2[m][i] = fz;

  for (int nc = 0; nc < 4; nc++) {
    f32x4 acc1[2][6];
    #pragma unroll
    for (int m = 0; m < 2; m++)
      #pragma unroll
      for (int i = 0; i < 6; i++) acc1[m][i] = fz;
    #pragma unroll
    for (int ks = 0; ks < 3; ks++) {
      bf16x8 bw[6];
      #pragma unroll
      for (int nt = 0; nt < 6; nt++)
        bw[nt] = *(const bf16x8*)(img + IW1 + ((nc * 3 + ks) * 6 + nt) * 512 + l * 8);
      #pragma unroll
      for (int m = 0; m < 2; m++) {
        bf16x8 af = *(const bf16x8*)&s_a[(w * 32 + m * 16 + l15) * 104 + ks * 32 + quad * 8];
        #pragma unroll
        for (int nt = 0; nt < 6; nt++)
          acc1[m][nt] = __builtin_amdgcn_mfma_f32_16x16x32_bf16(af, bw[nt], acc1[m][nt], 0, 0, 0);
      }
    }
    // ---- GELU -> s_h (wave-private rows) ----
    #pragma unroll
    for (int m = 0; m < 2; m++)
      #pragma unroll
      for (int nt = 0; nt < 6; nt++) {
        int col = nt * 16 + l15;
        float bv = fc1_b[nc * 96 + col];
        #pragma unroll
        for (int r = 0; r < 4; r++) {
          float z = acc1[m][nt][r] + bv;
          float g = 0.5f * z * (1.f + erff(z * 0.70710678118654752f));
          s_h[(w * 32 + m * 16 + quad * 4 + r) * 104 + col] = (short)f2us(g);
        }
      }
    // ---- GEMM2 partial ----
    #pragma unroll
    for (int ks = 0; ks < 3; ks++) {
      bf16x8 bw[6];
      #pragma unroll
      for (int nt = 0; nt < 6; nt++)
        bw[nt] = *(const bf16x8*)(img + IW2 + ((nc * 3 + ks) * 6 + nt) * 512 + l * 8);
      #pragma unroll
      for (int m = 0; m < 2; m++) {
        bf16x8 af = *(const bf16x8*)&s_h[(w * 32 + m * 16 + l15) * 104 + ks * 32 + quad * 8];
        #pragma unroll
        for (int nt = 0; nt < 6; nt++)
          acc2[m][nt] = __builtin_amdgcn_mfma_f32_16x16x32_bf16(af, bw[nt], acc2[m][nt], 0, 0, 0);
      }
    }
  }

  // ---- epilogue: out = x2 + mlp + fc2_b (spatial scatter) ----
  #pragma unroll
  for (int m = 0; m < 2; m++)
    #pragma unroll
    for (int r = 0; r < 4; r++)
      #pragma unroll
      for (int nt = 0; nt < 6; nt++)
        out[gg[m][r] * 96 + nt * 16 + l15] = x2[m][nt][r] + acc2[m][nt][r] + f2[nt];
}

extern "C" void kernel_launch(void* const* d_in, const int* in_sizes, int n_in,
                              void* d_out, int out_size, void* d_ws, size_t ws_size,
                              hipStream_t stream) {
  const float* x      = (const float*)d_in[0];
  const float* n1g    = (const float*)d_in[2];
  const float* n1b    = (const float*)d_in[3];
  const float* qkv_w  = (const float*)d_in[4];
  const float* qkv_b  = (const float*)d_in[5];
  const float* proj_w = (const float*)d_in[6];
  const float* proj_b = (const float*)d_in[7];
  const float* n2g    = (const float*)d_in[8];
  const float* n2b    = (const float*)d_in[9];
  const float* fc1_w  = (const float*)d_in[10];
  const float* fc1_b  = (const float*)d_in[11];
  const float* fc2_w  = (const float*)d_in[12];
  const float* fc2_b  = (const float*)d_in[13];
  float* out = (float*)d_out;

  // ws: xn bf16 (25,165,824 B) | img (227,328 B) | O bf16 (25,165,824 B)
  char* ws = (char*)d_ws;
  unsigned short* xn  = (unsigned short*)ws;
  unsigned short* img = (unsigned short*)(ws + 25165824u);
  unsigned short* og  = (unsigned short*)(ws + 25165824u + 227328u);

  k_prepw<<<IMG_SHORTS / 256, 256, 0, stream>>>(fc1_w, fc2_w, qkv_w, proj_w, img);
  k_ln1<<<TOK / 128, 256, 0, stream>>>(x, n1g, n1b, xn);
  k_win<<<BWIN, 256, 0, stream>>>(xn, img, qkv_b, og);
  k_pm<<<TOK / 128, 256, 0, stream>>>(og, x, img, proj_b, n2g, n2b, fc1_b, fc2_b, out);
}

// Round 7
// 284.544 us; speedup vs baseline: 1.4975x; 1.0520x over previous
//
#include <hip/hip_runtime.h>

#define TOK   131072
#define BWIN  512

typedef __attribute__((ext_vector_type(8))) short bf16x8;
typedef __attribute__((ext_vector_type(4))) short bf16x4;
typedef __attribute__((ext_vector_type(4))) float f32x4;

__device__ __forceinline__ unsigned short f2us(float f) {   // RNE f32->bf16 bits
  union { float f; unsigned int i; } x; x.f = f;
  return (unsigned short)((x.i + 0x7fffu + ((x.i >> 16) & 1u)) >> 16);
}
__device__ __forceinline__ unsigned cvtpk(float lo, float hi) {  // 2xf32 -> packed bf16
  unsigned r;
  asm("v_cvt_pk_bf16_f32 %0, %1, %2" : "=v"(r) : "v"(lo), "v"(hi));
  return r;
}
union U8 { uint2 u; bf16x4 v; };
union B8 { bf16x8 v; unsigned u[4]; };

// branch-free erf-based GELU (A&S 7.1.26, |err|<1.5e-7 on erf)
__device__ __forceinline__ float gelu_f(float z) {
  const float u = fabsf(z) * 0.70710678118654752f;
  float t;
  asm("v_rcp_f32 %0, %1" : "=v"(t) : "v"(fmaf(0.3275911f, u, 1.f)));
  float poly = t * (0.254829592f + t * (-0.284496736f + t * (1.421413741f +
               t * (-1.453152027f + t * 1.061405429f))));
  float er = 1.f - poly * __expf(-u * u);     // erf(u), u>=0
  er = copysignf(er, z);
  return 0.5f * z * (1.f + er);
}

// ---- fragment-order bf16 weight images in ws (short offsets) ----
// Each fragment = 512 shorts (1 KB): lane l owns shorts [l*8, l*8+8).
// W1:   frag(nc,ks,nt) : fc1 B-operand  -> 4*3*6 = 72 frags
// W2:   frag(nc,ks,nt) : fc2 B-operand  -> 72 frags
// QKV:  frag(h,ks,mt)  : qkv A-operand  -> 4*3*5 = 60 frags (rows>=72 zero)
// PROJ: frag(ks,nt)    : proj B-operand, full K=96 -> 3*6 = 18 frags
#define IW1   0
#define IW2   36864
#define IQKV  73728
#define IPROJ 104448
#define IMG_SHORTS 113664

// ---------------- P0a: build fragment-order bf16 weight images ----------------
__global__ __launch_bounds__(256) void k_prepw(
    const float* __restrict__ fc1_w, const float* __restrict__ fc2_w,
    const float* __restrict__ qkv_w, const float* __restrict__ proj_w,
    unsigned short* __restrict__ img) {
  int i = blockIdx.x * 256 + threadIdx.x;    // 0..113663
  const int l = (i >> 3) & 63, j = i & 7;
  const int quad = l >> 4, l15 = l & 15;
  float v = 0.f;
  if (i < 36864) {                                        // W1 fragments
    int f = i >> 9; int nc = f / 18, rem = f - nc * 18;
    int ks = rem / 6, nt = rem - ks * 6;
    v = fc1_w[(size_t)(nc * 96 + nt * 16 + l15) * 96 + ks * 32 + quad * 8 + j];
  } else if (i < 73728) {                                 // W2 fragments
    int f = (i - 36864) >> 9; int nc = f / 18, rem = f - nc * 18;
    int ks = rem / 6, nt = rem - ks * 6;
    v = fc2_w[(size_t)(nt * 16 + l15) * 384 + nc * 96 + ks * 32 + quad * 8 + j];
  } else if (i < 104448) {                                // QKV A-fragments
    int f = (i - 73728) >> 9; int h = f / 15, rem = f - h * 15;
    int ks = rem / 5, mt = rem - ks * 5;
    int e = mt * 16 + l15;
    if (e < 72) {
      int grp = e / 24, rr = e - grp * 24;
      v = qkv_w[(size_t)(grp * 96 + h * 24 + rr) * 96 + ks * 32 + quad * 8 + j];
    }
  } else {                                                // proj B-fragments (full K)
    int f = (i - 104448) >> 9; int ks = f / 6, nt = f - ks * 6;
    v = proj_w[(size_t)(nt * 16 + l15) * 96 + ks * 32 + quad * 8 + j];
  }
  img[i] = f2us(v);
}

// ---- k_win: fused LN1 + QKV + attention; O (normalized, bf16) -> og ---------
// LN1 is computed in-register: lane (quad,l15) owns channels ks*32+quad*8+..8
// of token q0+nt*16+l15; stats via shfl_xor(16/32) across the 4 quads.
// B-fragments (48 VGPRs) persist across all 4 heads -> xn buffer eliminated.
// LDS: s_k [256][36] + s_vt [32][260] + labels = 35,328 B
__global__ __launch_bounds__(256, 2) void k_win(
    const float* __restrict__ x,
    const unsigned short* __restrict__ img,
    const float* __restrict__ n1g, const float* __restrict__ n1b,
    const float* __restrict__ qkv_b,
    unsigned short* __restrict__ og) {
  __shared__ __align__(16) short s_k[256 * 36];    // K  [tok][36], e 24..31 zero
  __shared__ __align__(16) short s_vt[32 * 260];   // V^T [e][tok], rows 24..31 zero
  __shared__ unsigned char s_lb[256];

  const int tid = threadIdx.x;
  const int w = tid >> 6, l = tid & 63, quad = l >> 4, l15 = l & 15;
  const int q0 = w * 64;                       // wave's 64-token strip
  const int b_ = blockIdx.x;
  const int batch = b_ >> 8, wi = b_ & 255;
  const int wd = (wi >> 6) & 3, wh = (wi >> 4) & 3, ww = (wi >> 2) & 3, wt = wi & 3;
  const float scale = 0.20412414523193154f;    // 24^-0.5
  const f32x4 fz = {0.f, 0.f, 0.f, 0.f};

  // ---- phase 0: labels + zero pads ----
  {
    const int n = tid;
    const int aa = (n >> 6) & 3, bb = (n >> 4) & 3, cc = (n >> 2) & 3, dd = n & 3;
    const int p0 = wd * 4 + aa, p1 = wh * 4 + bb, p2 = ww * 4 + cc, p3 = wt * 4 + dd;
    const int r0 = p0 >= 14 ? 2 : (p0 >= 12 ? 1 : 0);
    const int r1 = p1 >= 14 ? 2 : (p1 >= 12 ? 1 : 0);
    const int r2 = p2 >= 14 ? 2 : (p2 >= 12 ? 1 : 0);
    const int r3 = p3 >= 14 ? 2 : (p3 >= 12 ? 1 : 0);
    s_lb[n] = (unsigned char)(((r0 * 3 + r1) * 3 + r2) * 3 + r3);
    *(uint2*)&s_k[n * 36 + 24] = make_uint2(0u, 0u);   // e 24..27
    *(uint2*)&s_k[n * 36 + 28] = make_uint2(0u, 0u);   // e 28..31
    unsigned int* vz = (unsigned int*)(s_vt + 24 * 260);
    for (int i = tid; i < 8 * 130; i += 256) vz[i] = 0u;  // V rows 24..31 = 0
  }

  // ---- fused LN1 -> bf16 B-fragments in registers (held across all heads) ----
  B8 bx[4][3];                                  // [nt][ks], 48 VGPRs
  {
    float gch[24], bch[24];
    #pragma unroll
    for (int ks = 0; ks < 3; ks++) {
      float4 g0 = *(const float4*)(n1g + ks * 32 + quad * 8);
      float4 g1 = *(const float4*)(n1g + ks * 32 + quad * 8 + 4);
      float4 b0 = *(const float4*)(n1b + ks * 32 + quad * 8);
      float4 b1 = *(const float4*)(n1b + ks * 32 + quad * 8 + 4);
      gch[ks*8+0]=g0.x; gch[ks*8+1]=g0.y; gch[ks*8+2]=g0.z; gch[ks*8+3]=g0.w;
      gch[ks*8+4]=g1.x; gch[ks*8+5]=g1.y; gch[ks*8+6]=g1.z; gch[ks*8+7]=g1.w;
      bch[ks*8+0]=b0.x; bch[ks*8+1]=b0.y; bch[ks*8+2]=b0.z; bch[ks*8+3]=b0.w;
      bch[ks*8+4]=b1.x; bch[ks*8+5]=b1.y; bch[ks*8+6]=b1.z; bch[ks*8+7]=b1.w;
    }
    #pragma unroll
    for (int nt = 0; nt < 4; nt++) {
      const int tok = q0 + nt * 16 + l15;
      const int aa = (tok >> 6) & 3, bb = (tok >> 4) & 3, cc = (tok >> 2) & 3, dd = tok & 3;
      const int sd = (wd * 4 + aa + 2) & 15, sh_ = (wh * 4 + bb + 2) & 15;
      const int sw_ = (ww * 4 + cc + 2) & 15, st_ = (wt * 4 + dd + 2) & 15;
      const size_t gg = ((((size_t)(batch * 16 + sd) * 16 + sh_) * 16 + sw_) * 16 + st_);
      const float* xp = x + gg * 96 + quad * 8;
      float v[24];
      float s = 0.f, q = 0.f;
      #pragma unroll
      for (int ks = 0; ks < 3; ks++) {
        float4 f0 = *(const float4*)(xp + ks * 32);
        float4 f1 = *(const float4*)(xp + ks * 32 + 4);
        v[ks*8+0]=f0.x; v[ks*8+1]=f0.y; v[ks*8+2]=f0.z; v[ks*8+3]=f0.w;
        v[ks*8+4]=f1.x; v[ks*8+5]=f1.y; v[ks*8+6]=f1.z; v[ks*8+7]=f1.w;
        s += (f0.x + f0.y) + (f0.z + f0.w) + (f1.x + f1.y) + (f1.z + f1.w);
        q += f0.x*f0.x + f0.y*f0.y + f0.z*f0.z + f0.w*f0.w
           + f1.x*f1.x + f1.y*f1.y + f1.z*f1.z + f1.w*f1.w;
      }
      s += __shfl_xor(s, 16, 64); q += __shfl_xor(q, 16, 64);
      s += __shfl_xor(s, 32, 64); q += __shfl_xor(q, 32, 64);
      const float mu = s * (1.f / 96.f);
      const float var = q * (1.f / 96.f) - mu * mu;
      const float rs = rsqrtf(fmaxf(var, 0.f) + 1e-5f);
      #pragma unroll
      for (int ks = 0; ks < 3; ks++)
        #pragma unroll
        for (int jj = 0; jj < 4; jj++) {
          const int c = ks * 8 + 2 * jj;
          bx[nt][ks].u[jj] = cvtpk((v[c]     - mu) * rs * gch[c]     + bch[c],
                                   (v[c + 1] - mu) * rs * gch[c + 1] + bch[c + 1]);
        }
    }
  }
  __syncthreads();

  const unsigned short* wq = img + IQKV;

  for (int h = 0; h < 4; h++) {
    // ---- QKV GEMM (swapped, x32): weights global->reg, activations in reg ----
    f32x4 acc[5][4];
    #pragma unroll
    for (int mt = 0; mt < 5; mt++)
      #pragma unroll
      for (int nt = 0; nt < 4; nt++) acc[mt][nt] = fz;
    #pragma unroll
    for (int ks = 0; ks < 3; ks++) {
      bf16x8 aw[5];
      #pragma unroll
      for (int mt = 0; mt < 5; mt++)
        aw[mt] = *(const bf16x8*)(wq + ((h * 3 + ks) * 5 + mt) * 512 + l * 8);
      #pragma unroll
      for (int nt = 0; nt < 4; nt++) {
        const bf16x8 bxv = bx[nt][ks].v;
        #pragma unroll
        for (int mt = 0; mt < 5; mt++)
          acc[mt][nt] = __builtin_amdgcn_mfma_f32_16x16x32_bf16(aw[mt], bxv, acc[mt][nt], 0, 0, 0);
      }
    }
    // ---- Q: pack in-register (B-operand of 16x16x16, e chunks mt=0,1) ----
    U8 qq[2][4];
    #pragma unroll
    for (int mt = 0; mt < 2; mt++) {
      const int e0 = mt * 16 + quad * 4;
      float b0 = qkv_b[h * 24 + e0],     b1 = qkv_b[h * 24 + e0 + 1];
      float b2 = qkv_b[h * 24 + e0 + 2], b3 = qkv_b[h * 24 + e0 + 3];
      #pragma unroll
      for (int nt = 0; nt < 4; nt++) {
        qq[mt][nt].u.x = cvtpk((acc[mt][nt][0] + b0) * scale, (acc[mt][nt][1] + b1) * scale);
        qq[mt][nt].u.y = cvtpk((acc[mt][nt][2] + b2) * scale, (acc[mt][nt][3] + b3) * scale);
      }
    }
    // ---- scatter K (uint2) / V^T (shorts) to LDS ----
    #pragma unroll
    for (int mt = 1; mt < 5; mt++) {
      const int e0 = mt * 16 + quad * 4;
      #pragma unroll
      for (int nt = 0; nt < 4; nt++) {
        const int tok = q0 + nt * 16 + l15;
        if (e0 >= 24 && e0 < 48) {       // K
          const int e = e0 - 24;
          uint2 pk;
          pk.x = cvtpk(acc[mt][nt][0] + qkv_b[96 + h * 24 + e],
                       acc[mt][nt][1] + qkv_b[96 + h * 24 + e + 1]);
          pk.y = cvtpk(acc[mt][nt][2] + qkv_b[96 + h * 24 + e + 2],
                       acc[mt][nt][3] + qkv_b[96 + h * 24 + e + 3]);
          *(uint2*)&s_k[tok * 36 + e] = pk;
        } else if (e0 >= 48 && e0 < 72) {  // V^T
          const int e = e0 - 48;
          #pragma unroll
          for (int r = 0; r < 4; r++)
            s_vt[(e + r) * 260 + tok] = (short)f2us(acc[mt][nt][r] + qkv_b[192 + h * 24 + e + r]);
        }
      }
    }
    __syncthreads();                                           // K/V visible
    // ---- attention: per 16-query tile, P and Q never touch LDS ----
    #pragma unroll 1
    for (int mt4 = 0; mt4 < 4; mt4++) {
      const int qt0 = q0 + mt4 * 16;
      f32x4 sc[16];
      #pragma unroll
      for (int km = 0; km < 16; km++) sc[km] = fz;
      const bf16x4 bq0 = qq[0][mt4].v, bq1 = qq[1][mt4].v;
      __builtin_amdgcn_s_setprio(1);
      #pragma unroll
      for (int km = 0; km < 16; km++) {
        bf16x4 ak0 = *(const bf16x4*)&s_k[(km * 16 + l15) * 36 + quad * 4];
        bf16x4 ak1 = *(const bf16x4*)&s_k[(km * 16 + l15) * 36 + 16 + quad * 4];
        sc[km] = __builtin_amdgcn_mfma_f32_16x16x16bf16_1k(ak0, bq0, sc[km], 0, 0, 0);
        sc[km] = __builtin_amdgcn_mfma_f32_16x16x16bf16_1k(ak1, bq1, sc[km], 0, 0, 0);
      }
      __builtin_amdgcn_s_setprio(0);
      // ---- masked exp (in place) + in-register row-sum ----
      const unsigned lq = s_lb[qt0 + l15];
      float rsum = 0.f;
      #pragma unroll
      for (int km = 0; km < 16; km++) {
        unsigned lj = *(const unsigned*)&s_lb[km * 16 + quad * 4];
        float p0 = ((lj & 255u)         == lq) ? __expf(sc[km][0]) : 0.f;
        float p1 = (((lj >> 8) & 255u)  == lq) ? __expf(sc[km][1]) : 0.f;
        float p2 = (((lj >> 16) & 255u) == lq) ? __expf(sc[km][2]) : 0.f;
        float p3 = ((lj >> 24)          == lq) ? __expf(sc[km][3]) : 0.f;
        sc[km][0] = p0; sc[km][1] = p1; sc[km][2] = p2; sc[km][3] = p3;
        rsum += (p0 + p1) + (p2 + p3);
      }
      rsum += __shfl_xor(rsum, 16, 64);
      rsum += __shfl_xor(rsum, 32, 64);
      const float inv = 1.f / rsum;
      // ---- PV (x16): P fed straight from registers ----
      f32x4 ov0 = fz, ov1 = fz;
      __builtin_amdgcn_s_setprio(1);
      #pragma unroll
      for (int km = 0; km < 16; km++) {
        U8 bp;
        bp.u.x = cvtpk(sc[km][0], sc[km][1]);
        bp.u.y = cvtpk(sc[km][2], sc[km][3]);
        bf16x4 av0 = *(const bf16x4*)&s_vt[l15 * 260 + km * 16 + quad * 4];
        bf16x4 av1 = *(const bf16x4*)&s_vt[(16 + l15) * 260 + km * 16 + quad * 4];
        ov0 = __builtin_amdgcn_mfma_f32_16x16x16bf16_1k(av0, bp.v, ov0, 0, 0, 0);
        ov1 = __builtin_amdgcn_mfma_f32_16x16x16bf16_1k(av1, bp.v, ov1, 0, 0, 0);
      }
      __builtin_amdgcn_s_setprio(0);
      // ---- O (normalized, bf16) straight to global, window order ----
      uint2 o0, o1;
      o0.x = cvtpk(ov0[0] * inv, ov0[1] * inv);
      o0.y = cvtpk(ov0[2] * inv, ov0[3] * inv);
      o1.x = cvtpk(ov1[0] * inv, ov1[1] * inv);
      o1.y = cvtpk(ov1[2] * inv, ov1[3] * inv);
      size_t ob = ((size_t)b_ * 256 + qt0 + l15) * 96 + h * 24;
      *(uint2*)&og[ob + quad * 4] = o0;                  // e 0..15
      if (quad < 2) *(uint2*)&og[ob + 16 + quad * 4] = o1;  // e 16..23
    }
    __syncthreads();               // all waves done with s_k/s_vt for this head
  }
}

// ---- k_pm: fused proj + residual + LN2 + MLP + residual -> out --------------
// proj C-layout: token = t0+w*32+m*16+quad*4+r owned by 16 lanes (l15 varies),
// channel = nt*16+l15. LN2 stats via 4-step shfl_xor tree over the l15 group.
// s_a/s_h rows are wave-private -> ZERO barriers.
__global__ __launch_bounds__(256, 2) void k_pm(
    const unsigned short* __restrict__ og, const float* __restrict__ x,
    const unsigned short* __restrict__ img,
    const float* __restrict__ proj_b,
    const float* __restrict__ n2g, const float* __restrict__ n2b,
    const float* __restrict__ fc1_b, const float* __restrict__ fc2_b,
    float* __restrict__ out) {
  __shared__ __align__(16) short s_a[128 * 104];   // LN2 out (wave-private rows)
  __shared__ __align__(16) short s_h[128 * 104];   // GELU out (wave-private rows)

  const int tid = threadIdx.x;
  const int w = tid >> 6, l = tid & 63, quad = l >> 4, l15 = l & 15;
  const int t0 = blockIdx.x * 128;
  const f32x4 fz = {0.f, 0.f, 0.f, 0.f};

  // ---- per-lane channel constants (c = nt*16 + l15) ----
  float gn[6], bn[6], pb[6], f2[6];
  #pragma unroll
  for (int nt = 0; nt < 6; nt++) {
    int c = nt * 16 + l15;
    gn[nt] = n2g[c]; bn[nt] = n2b[c]; pb[nt] = proj_b[c]; f2[nt] = fc2_b[c];
  }

  // ---- phase 1: proj GEMM ----
  f32x4 pacc[2][6];
  #pragma unroll
  for (int m = 0; m < 2; m++)
    #pragma unroll
    for (int nt = 0; nt < 6; nt++) pacc[m][nt] = fz;
  #pragma unroll
  for (int ks = 0; ks < 3; ks++) {
    bf16x8 bw[6];
    #pragma unroll
    for (int nt = 0; nt < 6; nt++)
      bw[nt] = *(const bf16x8*)(img + IPROJ + (ks * 6 + nt) * 512 + l * 8);
    #pragma unroll
    for (int m = 0; m < 2; m++) {
      bf16x8 af = *(const bf16x8*)(og + (size_t)(t0 + w * 32 + m * 16 + l15) * 96 + ks * 32 + quad * 8);
      #pragma unroll
      for (int nt = 0; nt < 6; nt++)
        pacc[m][nt] = __builtin_amdgcn_mfma_f32_16x16x32_bf16(af, bw[nt], pacc[m][nt], 0, 0, 0);
    }
  }

  // ---- phase 2: residual x2 (regs) + LN2 stats (shfl tree) -> s_a bf16 ----
  float x2[2][6][4];
  size_t gg[2][4];
  #pragma unroll
  for (int m = 0; m < 2; m++) {
    #pragma unroll
    for (int r = 0; r < 4; r++) {
      const int T = t0 + w * 32 + m * 16 + quad * 4 + r;
      const int b_ = T >> 8, n = T & 255;
      const int batch = b_ >> 8, wi = b_ & 255;
      const int wd = (wi >> 6) & 3, wh = (wi >> 4) & 3, ww = (wi >> 2) & 3, wt = wi & 3;
      const int aa = (n >> 6) & 3, bb = (n >> 4) & 3, cc = (n >> 2) & 3, dd = n & 3;
      const int sd = (wd * 4 + aa + 2) & 15, sh = (wh * 4 + bb + 2) & 15;
      const int sw = (ww * 4 + cc + 2) & 15, st = (wt * 4 + dd + 2) & 15;
      gg[m][r] = ((((size_t)(batch * 16 + sd) * 16 + sh) * 16 + sw) * 16 + st);
      float s = 0.f, q = 0.f;
      #pragma unroll
      for (int nt = 0; nt < 6; nt++) {
        float v = x[gg[m][r] * 96 + nt * 16 + l15] + pb[nt] + pacc[m][nt][r];
        x2[m][nt][r] = v;
        s += v; q += v * v;
      }
      s += __shfl_xor(s, 1); q += __shfl_xor(q, 1);
      s += __shfl_xor(s, 2); q += __shfl_xor(q, 2);
      s += __shfl_xor(s, 4); q += __shfl_xor(q, 4);
      s += __shfl_xor(s, 8); q += __shfl_xor(q, 8);
      const float mu = s * (1.f / 96.f);
      const float var = q * (1.f / 96.f) - mu * mu;
      const float rs = rsqrtf(fmaxf(var, 0.f) + 1e-5f);
      const int tr = w * 32 + m * 16 + quad * 4 + r;
      #pragma unroll
      for (int nt = 0; nt < 6; nt++)
        s_a[tr * 104 + nt * 16 + l15] =
            (short)f2us((x2[m][nt][r] - mu) * rs * gn[nt] + bn[nt]);
    }
  }
  // s_a rows [w*32, w*32+32) written and read by wave w only -> no barrier.

  // ---- phase 3: MLP ----
  f32x4 acc2[2][6];
  #pragma unroll
  for (int m = 0; m < 2; m++)
    #pragma unroll
    for (int i = 0; i < 6; i++) acc2[m][i] = fz;

  for (int nc = 0; nc < 4; nc++) {
    f32x4 acc1[2][6];
    #pragma unroll
    for (int m = 0; m < 2; m++)
      #pragma unroll
      for (int i = 0; i < 6; i++) acc1[m][i] = fz;
    #pragma unroll
    for (int ks = 0; ks < 3; ks++) {
      bf16x8 bw[6];
      #pragma unroll
      for (int nt = 0; nt < 6; nt++)
        bw[nt] = *(const bf16x8*)(img + IW1 + ((nc * 3 + ks) * 6 + nt) * 512 + l * 8);
      #pragma unroll
      for (int m = 0; m < 2; m++) {
        bf16x8 af = *(const bf16x8*)&s_a[(w * 32 + m * 16 + l15) * 104 + ks * 32 + quad * 8];
        #pragma unroll
        for (int nt = 0; nt < 6; nt++)
          acc1[m][nt] = __builtin_amdgcn_mfma_f32_16x16x32_bf16(af, bw[nt], acc1[m][nt], 0, 0, 0);
      }
    }
    // ---- GELU -> s_h (wave-private rows) ----
    #pragma unroll
    for (int m = 0; m < 2; m++)
      #pragma unroll
      for (int nt = 0; nt < 6; nt++) {
        int col = nt * 16 + l15;
        float bv = fc1_b[nc * 96 + col];
        #pragma unroll
        for (int r = 0; r < 4; r++) {
          float z = acc1[m][nt][r] + bv;
          s_h[(w * 32 + m * 16 + quad * 4 + r) * 104 + col] = (short)f2us(gelu_f(z));
        }
      }
    // ---- GEMM2 partial ----
    #pragma unroll
    for (int ks = 0; ks < 3; ks++) {
      bf16x8 bw[6];
      #pragma unroll
      for (int nt = 0; nt < 6; nt++)
        bw[nt] = *(const bf16x8*)(img + IW2 + ((nc * 3 + ks) * 6 + nt) * 512 + l * 8);
      #pragma unroll
      for (int m = 0; m < 2; m++) {
        bf16x8 af = *(const bf16x8*)&s_h[(w * 32 + m * 16 + l15) * 104 + ks * 32 + quad * 8];
        #pragma unroll
        for (int nt = 0; nt < 6; nt++)
          acc2[m][nt] = __builtin_amdgcn_mfma_f32_16x16x32_bf16(af, bw[nt], acc2[m][nt], 0, 0, 0);
      }
    }
  }

  // ---- epilogue: out = x2 + mlp + fc2_b (spatial scatter) ----
  #pragma unroll
  for (int m = 0; m < 2; m++)
    #pragma unroll
    for (int r = 0; r < 4; r++)
      #pragma unroll
      for (int nt = 0; nt < 6; nt++)
        out[gg[m][r] * 96 + nt * 16 + l15] = x2[m][nt][r] + acc2[m][nt][r] + f2[nt];
}

extern "C" void kernel_launch(void* const* d_in, const int* in_sizes, int n_in,
                              void* d_out, int out_size, void* d_ws, size_t ws_size,
                              hipStream_t stream) {
  const float* x      = (const float*)d_in[0];
  const float* n1g    = (const float*)d_in[2];
  const float* n1b    = (const float*)d_in[3];
  const float* qkv_w  = (const float*)d_in[4];
  const float* qkv_b  = (const float*)d_in[5];
  const float* proj_w = (const float*)d_in[6];
  const float* proj_b = (const float*)d_in[7];
  const float* n2g    = (const float*)d_in[8];
  const float* n2b    = (const float*)d_in[9];
  const float* fc1_w  = (const float*)d_in[10];
  const float* fc1_b  = (const float*)d_in[11];
  const float* fc2_w  = (const float*)d_in[12];
  const float* fc2_b  = (const float*)d_in[13];
  float* out = (float*)d_out;

  // ws: img (227,328 B) | O bf16 (25,165,824 B)
  char* ws = (char*)d_ws;
  unsigned short* img = (unsigned short*)ws;
  unsigned short* og  = (unsigned short*)(ws + 227328u);

  k_prepw<<<IMG_SHORTS / 256, 256, 0, stream>>>(fc1_w, fc2_w, qkv_w, proj_w, img);
  k_win<<<BWIN, 256, 0, stream>>>(x, img, n1g, n1b, qkv_b, og);
  k_pm<<<TOK / 128, 256, 0, stream>>>(og, x, img, proj_b, n2g, n2b, fc1_b, fc2_b, out);
}

// Round 10
// 283.413 us; speedup vs baseline: 1.5035x; 1.0040x over previous
//
#include <hip/hip_runtime.h>

#define TOK   131072
#define BWIN  512

typedef __attribute__((ext_vector_type(8))) short bf16x8;
typedef __attribute__((ext_vector_type(4))) short bf16x4;
typedef __attribute__((ext_vector_type(4))) float f32x4;

__device__ __forceinline__ unsigned short f2us(float f) {   // RNE f32->bf16 bits
  union { float f; unsigned int i; } x; x.f = f;
  return (unsigned short)((x.i + 0x7fffu + ((x.i >> 16) & 1u)) >> 16);
}
__device__ __forceinline__ unsigned cvtpk(float lo, float hi) {  // 2xf32 -> packed bf16
  unsigned r;
  asm("v_cvt_pk_bf16_f32 %0, %1, %2" : "=v"(r) : "v"(lo), "v"(hi));
  return r;
}
union U8 { uint2 u; bf16x4 v; };
union B8 { bf16x8 v; unsigned u[4]; };

// branch-free erf-based GELU (A&S 7.1.26, |err|<1.5e-7 on erf)
__device__ __forceinline__ float gelu_f(float z) {
  const float u = fabsf(z) * 0.70710678118654752f;
  float t;
  asm("v_rcp_f32 %0, %1" : "=v"(t) : "v"(fmaf(0.3275911f, u, 1.f)));
  float poly = t * (0.254829592f + t * (-0.284496736f + t * (1.421413741f +
               t * (-1.453152027f + t * 1.061405429f))));
  float er = 1.f - poly * __expf(-u * u);     // erf(u), u>=0
  er = copysignf(er, z);
  return 0.5f * z * (1.f + er);
}

// ---- fragment-order bf16 weight images in ws (short offsets) ----
#define IW1   0
#define IW2   36864
#define IQKV  73728
#define IPROJ 104448
#define IMG_SHORTS 113664

// ---------------- P0a: build fragment-order bf16 weight images ----------------
__global__ __launch_bounds__(256) void k_prepw(
    const float* __restrict__ fc1_w, const float* __restrict__ fc2_w,
    const float* __restrict__ qkv_w, const float* __restrict__ proj_w,
    unsigned short* __restrict__ img) {
  int i = blockIdx.x * 256 + threadIdx.x;    // 0..113663
  const int l = (i >> 3) & 63, j = i & 7;
  const int quad = l >> 4, l15 = l & 15;
  float v = 0.f;
  if (i < 36864) {                                        // W1 fragments
    int f = i >> 9; int nc = f / 18, rem = f - nc * 18;
    int ks = rem / 6, nt = rem - ks * 6;
    v = fc1_w[(size_t)(nc * 96 + nt * 16 + l15) * 96 + ks * 32 + quad * 8 + j];
  } else if (i < 73728) {                                 // W2 fragments
    int f = (i - 36864) >> 9; int nc = f / 18, rem = f - nc * 18;
    int ks = rem / 6, nt = rem - ks * 6;
    v = fc2_w[(size_t)(nt * 16 + l15) * 384 + nc * 96 + ks * 32 + quad * 8 + j];
  } else if (i < 104448) {                                // QKV A-fragments
    int f = (i - 73728) >> 9; int h = f / 15, rem = f - h * 15;
    int ks = rem / 5, mt = rem - ks * 5;
    int e = mt * 16 + l15;
    if (e < 72) {
      int grp = e / 24, rr = e - grp * 24;
      v = qkv_w[(size_t)(grp * 96 + h * 24 + rr) * 96 + ks * 32 + quad * 8 + j];
    }
  } else {                                                // proj B-fragments (full K)
    int f = (i - 104448) >> 9; int ks = f / 6, nt = f - ks * 6;
    v = proj_w[(size_t)(nt * 16 + l15) * 96 + ks * 32 + quad * 8 + j];
  }
  img[i] = f2us(v);
}

// ---- k_win: fused LN1 + QKV + attention (R7 numerics, og head-blocked) ------
// og layout [h][tok][24]: per (tile,head) store = 768 contiguous bytes.
__global__ __launch_bounds__(256, 2) void k_win(
    const float* __restrict__ x,
    const unsigned short* __restrict__ img,
    const float* __restrict__ n1g, const float* __restrict__ n1b,
    const float* __restrict__ qkv_b,
    unsigned short* __restrict__ og) {
  __shared__ __align__(16) short s_k[256 * 36];    // K  [tok][36], e 24..31 zero
  __shared__ __align__(16) short s_vt[32 * 260];   // V^T [e][tok], rows 24..31 zero
  __shared__ unsigned char s_lb[256];

  const int tid = threadIdx.x;
  const int w = tid >> 6, l = tid & 63, quad = l >> 4, l15 = l & 15;
  const int q0 = w * 64;                       // wave's 64-token strip
  const int b_ = blockIdx.x;
  const int batch = b_ >> 8, wi = b_ & 255;
  const int wd = (wi >> 6) & 3, wh = (wi >> 4) & 3, ww = (wi >> 2) & 3, wt = wi & 3;
  const float scale = 0.20412414523193154f;    // 24^-0.5
  const f32x4 fz = {0.f, 0.f, 0.f, 0.f};

  // ---- phase 0: labels + zero pads ----
  {
    const int n = tid;
    const int aa = (n >> 6) & 3, bb = (n >> 4) & 3, cc = (n >> 2) & 3, dd = n & 3;
    const int p0 = wd * 4 + aa, p1 = wh * 4 + bb, p2 = ww * 4 + cc, p3 = wt * 4 + dd;
    const int r0 = p0 >= 14 ? 2 : (p0 >= 12 ? 1 : 0);
    const int r1 = p1 >= 14 ? 2 : (p1 >= 12 ? 1 : 0);
    const int r2 = p2 >= 14 ? 2 : (p2 >= 12 ? 1 : 0);
    const int r3 = p3 >= 14 ? 2 : (p3 >= 12 ? 1 : 0);
    s_lb[n] = (unsigned char)(((r0 * 3 + r1) * 3 + r2) * 3 + r3);
    *(uint2*)&s_k[n * 36 + 24] = make_uint2(0u, 0u);   // e 24..27
    *(uint2*)&s_k[n * 36 + 28] = make_uint2(0u, 0u);   // e 28..31
    unsigned int* vz = (unsigned int*)(s_vt + 24 * 260);
    for (int i = tid; i < 8 * 130; i += 256) vz[i] = 0u;  // V rows 24..31 = 0
  }

  // ---- fused LN1 -> bf16 B-fragments in registers (held across all heads) ----
  B8 bx[4][3];                                  // [nt][ks], 48 VGPRs
  {
    float gch[24], bch[24];
    #pragma unroll
    for (int ks = 0; ks < 3; ks++) {
      float4 g0 = *(const float4*)(n1g + ks * 32 + quad * 8);
      float4 g1 = *(const float4*)(n1g + ks * 32 + quad * 8 + 4);
      float4 b0 = *(const float4*)(n1b + ks * 32 + quad * 8);
      float4 b1 = *(const float4*)(n1b + ks * 32 + quad * 8 + 4);
      gch[ks*8+0]=g0.x; gch[ks*8+1]=g0.y; gch[ks*8+2]=g0.z; gch[ks*8+3]=g0.w;
      gch[ks*8+4]=g1.x; gch[ks*8+5]=g1.y; gch[ks*8+6]=g1.z; gch[ks*8+7]=g1.w;
      bch[ks*8+0]=b0.x; bch[ks*8+1]=b0.y; bch[ks*8+2]=b0.z; bch[ks*8+3]=b0.w;
      bch[ks*8+4]=b1.x; bch[ks*8+5]=b1.y; bch[ks*8+6]=b1.z; bch[ks*8+7]=b1.w;
    }
    #pragma unroll
    for (int nt = 0; nt < 4; nt++) {
      const int tok = q0 + nt * 16 + l15;
      const int aa = (tok >> 6) & 3, bb = (tok >> 4) & 3, cc = (tok >> 2) & 3, dd = tok & 3;
      const int sd = (wd * 4 + aa + 2) & 15, sh_ = (wh * 4 + bb + 2) & 15;
      const int sw_ = (ww * 4 + cc + 2) & 15, st_ = (wt * 4 + dd + 2) & 15;
      const size_t gg = ((((size_t)(batch * 16 + sd) * 16 + sh_) * 16 + sw_) * 16 + st_);
      const float* xp = x + gg * 96 + quad * 8;
      float v[24];
      float s = 0.f, q = 0.f;
      #pragma unroll
      for (int ks = 0; ks < 3; ks++) {
        float4 f0 = *(const float4*)(xp + ks * 32);
        float4 f1 = *(const float4*)(xp + ks * 32 + 4);
        v[ks*8+0]=f0.x; v[ks*8+1]=f0.y; v[ks*8+2]=f0.z; v[ks*8+3]=f0.w;
        v[ks*8+4]=f1.x; v[ks*8+5]=f1.y; v[ks*8+6]=f1.z; v[ks*8+7]=f1.w;
        s += (f0.x + f0.y) + (f0.z + f0.w) + (f1.x + f1.y) + (f1.z + f1.w);
        q += f0.x*f0.x + f0.y*f0.y + f0.z*f0.z + f0.w*f0.w
           + f1.x*f1.x + f1.y*f1.y + f1.z*f1.z + f1.w*f1.w;
      }
      s += __shfl_xor(s, 16, 64); q += __shfl_xor(q, 16, 64);
      s += __shfl_xor(s, 32, 64); q += __shfl_xor(q, 32, 64);
      const float mu = s * (1.f / 96.f);
      const float var = q * (1.f / 96.f) - mu * mu;
      const float rs = rsqrtf(fmaxf(var, 0.f) + 1e-5f);
      #pragma unroll
      for (int ks = 0; ks < 3; ks++)
        #pragma unroll
        for (int jj = 0; jj < 4; jj++) {
          const int c = ks * 8 + 2 * jj;
          bx[nt][ks].u[jj] = cvtpk((v[c]     - mu) * rs * gch[c]     + bch[c],
                                   (v[c + 1] - mu) * rs * gch[c + 1] + bch[c + 1]);
        }
    }
  }
  __syncthreads();

  const unsigned short* wq = img + IQKV;

  for (int h = 0; h < 4; h++) {
    // ---- QKV GEMM (swapped, x32) ----
    f32x4 acc[5][4];
    #pragma unroll
    for (int mt = 0; mt < 5; mt++)
      #pragma unroll
      for (int nt = 0; nt < 4; nt++) acc[mt][nt] = fz;
    #pragma unroll
    for (int ks = 0; ks < 3; ks++) {
      bf16x8 aw[5];
      #pragma unroll
      for (int mt = 0; mt < 5; mt++)
        aw[mt] = *(const bf16x8*)(wq + ((h * 3 + ks) * 5 + mt) * 512 + l * 8);
      #pragma unroll
      for (int nt = 0; nt < 4; nt++) {
        const bf16x8 bxv = bx[nt][ks].v;
        #pragma unroll
        for (int mt = 0; mt < 5; mt++)
          acc[mt][nt] = __builtin_amdgcn_mfma_f32_16x16x32_bf16(aw[mt], bxv, acc[mt][nt], 0, 0, 0);
      }
    }
    // ---- Q: pack in-register (B-operand of 16x16x16, e chunks mt=0,1) ----
    U8 qq[2][4];
    #pragma unroll
    for (int mt = 0; mt < 2; mt++) {
      const int e0 = mt * 16 + quad * 4;
      float b0 = qkv_b[h * 24 + e0],     b1 = qkv_b[h * 24 + e0 + 1];
      float b2 = qkv_b[h * 24 + e0 + 2], b3 = qkv_b[h * 24 + e0 + 3];
      #pragma unroll
      for (int nt = 0; nt < 4; nt++) {
        qq[mt][nt].u.x = cvtpk((acc[mt][nt][0] + b0) * scale, (acc[mt][nt][1] + b1) * scale);
        qq[mt][nt].u.y = cvtpk((acc[mt][nt][2] + b2) * scale, (acc[mt][nt][3] + b3) * scale);
      }
    }
    // ---- scatter K (uint2) / V^T (shorts) to LDS ----
    #pragma unroll
    for (int mt = 1; mt < 5; mt++) {
      const int e0 = mt * 16 + quad * 4;
      #pragma unroll
      for (int nt = 0; nt < 4; nt++) {
        const int tok = q0 + nt * 16 + l15;
        if (e0 >= 24 && e0 < 48) {       // K
          const int e = e0 - 24;
          uint2 pk;
          pk.x = cvtpk(acc[mt][nt][0] + qkv_b[96 + h * 24 + e],
                       acc[mt][nt][1] + qkv_b[96 + h * 24 + e + 1]);
          pk.y = cvtpk(acc[mt][nt][2] + qkv_b[96 + h * 24 + e + 2],
                       acc[mt][nt][3] + qkv_b[96 + h * 24 + e + 3]);
          *(uint2*)&s_k[tok * 36 + e] = pk;
        } else if (e0 >= 48 && e0 < 72) {  // V^T
          const int e = e0 - 48;
          #pragma unroll
          for (int r = 0; r < 4; r++)
            s_vt[(e + r) * 260 + tok] = (short)f2us(acc[mt][nt][r] + qkv_b[192 + h * 24 + e + r]);
        }
      }
    }
    __syncthreads();                                           // K/V visible
    // ---- attention: per 16-query tile, P and Q never touch LDS ----
    #pragma unroll 1
    for (int mt4 = 0; mt4 < 4; mt4++) {
      const int qt0 = q0 + mt4 * 16;
      f32x4 sc[16];
      #pragma unroll
      for (int km = 0; km < 16; km++) sc[km] = fz;
      const bf16x4 bq0 = qq[0][mt4].v, bq1 = qq[1][mt4].v;
      __builtin_amdgcn_s_setprio(1);
      #pragma unroll
      for (int km = 0; km < 16; km++) {
        bf16x4 ak0 = *(const bf16x4*)&s_k[(km * 16 + l15) * 36 + quad * 4];
        bf16x4 ak1 = *(const bf16x4*)&s_k[(km * 16 + l15) * 36 + 16 + quad * 4];
        sc[km] = __builtin_amdgcn_mfma_f32_16x16x16bf16_1k(ak0, bq0, sc[km], 0, 0, 0);
        sc[km] = __builtin_amdgcn_mfma_f32_16x16x16bf16_1k(ak1, bq1, sc[km], 0, 0, 0);
      }
      __builtin_amdgcn_s_setprio(0);
      // ---- masked exp (in place) + in-register row-sum ----
      const unsigned lq = s_lb[qt0 + l15];
      float rsum = 0.f;
      #pragma unroll
      for (int km = 0; km < 16; km++) {
        unsigned lj = *(const unsigned*)&s_lb[km * 16 + quad * 4];
        float p0 = ((lj & 255u)         == lq) ? __expf(sc[km][0]) : 0.f;
        float p1 = (((lj >> 8) & 255u)  == lq) ? __expf(sc[km][1]) : 0.f;
        float p2 = (((lj >> 16) & 255u) == lq) ? __expf(sc[km][2]) : 0.f;
        float p3 = ((lj >> 24)          == lq) ? __expf(sc[km][3]) : 0.f;
        sc[km][0] = p0; sc[km][1] = p1; sc[km][2] = p2; sc[km][3] = p3;
        rsum += (p0 + p1) + (p2 + p3);
      }
      rsum += __shfl_xor(rsum, 16, 64);
      rsum += __shfl_xor(rsum, 32, 64);
      const float inv = 1.f / rsum;
      // ---- PV (x16): P fed straight from registers ----
      f32x4 ov0 = fz, ov1 = fz;
      __builtin_amdgcn_s_setprio(1);
      #pragma unroll
      for (int km = 0; km < 16; km++) {
        U8 bp;
        bp.u.x = cvtpk(sc[km][0], sc[km][1]);
        bp.u.y = cvtpk(sc[km][2], sc[km][3]);
        bf16x4 av0 = *(const bf16x4*)&s_vt[l15 * 260 + km * 16 + quad * 4];
        bf16x4 av1 = *(const bf16x4*)&s_vt[(16 + l15) * 260 + km * 16 + quad * 4];
        ov0 = __builtin_amdgcn_mfma_f32_16x16x16bf16_1k(av0, bp.v, ov0, 0, 0, 0);
        ov1 = __builtin_amdgcn_mfma_f32_16x16x16bf16_1k(av1, bp.v, ov1, 0, 0, 0);
      }
      __builtin_amdgcn_s_setprio(0);
      // ---- O (normalized, bf16) -> og head-blocked [h][tok][24] ----
      uint2 o0, o1;
      o0.x = cvtpk(ov0[0] * inv, ov0[1] * inv);
      o0.y = cvtpk(ov0[2] * inv, ov0[3] * inv);
      o1.x = cvtpk(ov1[0] * inv, ov1[1] * inv);
      o1.y = cvtpk(ov1[2] * inv, ov1[3] * inv);
      size_t ob = ((size_t)h * TOK + (size_t)b_ * 256 + qt0 + l15) * 24;
      *(uint2*)&og[ob + quad * 4] = o0;                        // e 0..15
      if (quad < 2) *(uint2*)&og[ob + 16 + quad * 4] = o1;     // e 16..23
    }
    __syncthreads();               // all waves done with s_k/s_vt for this head
  }
}

// ---- k_pm: fused proj + residual + LN2 + MLP + residual -> out --------------
__global__ __launch_bounds__(256, 2) void k_pm(
    const unsigned short* __restrict__ og, const float* __restrict__ x,
    const unsigned short* __restrict__ img,
    const float* __restrict__ proj_b,
    const float* __restrict__ n2g, const float* __restrict__ n2b,
    const float* __restrict__ fc1_b, const float* __restrict__ fc2_b,
    float* __restrict__ out) {
  __shared__ __align__(16) short s_a[128 * 104];   // LN2 out (wave-private rows)
  __shared__ __align__(16) short s_h[128 * 104];   // GELU out (wave-private rows)

  const int tid = threadIdx.x;
  const int w = tid >> 6, l = tid & 63, quad = l >> 4, l15 = l & 15;
  const int t0 = blockIdx.x * 128;
  const f32x4 fz = {0.f, 0.f, 0.f, 0.f};

  // ---- per-lane channel constants (c = nt*16 + l15) ----
  float gn[6], bn[6], pb[6], f2[6];
  #pragma unroll
  for (int nt = 0; nt < 6; nt++) {
    int c = nt * 16 + l15;
    gn[nt] = n2g[c]; bn[nt] = n2b[c]; pb[nt] = proj_b[c]; f2[nt] = fc2_b[c];
  }

  // ---- phase 1: proj GEMM (og head-blocked: chunk (ks,quad) -> head idx/3) ----
  f32x4 pacc[2][6];
  #pragma unroll
  for (int m = 0; m < 2; m++)
    #pragma unroll
    for (int nt = 0; nt < 6; nt++) pacc[m][nt] = fz;
  #pragma unroll
  for (int ks = 0; ks < 3; ks++) {
    bf16x8 bw[6];
    #pragma unroll
    for (int nt = 0; nt < 6; nt++)
      bw[nt] = *(const bf16x8*)(img + IPROJ + (ks * 6 + nt) * 512 + l * 8);
    const int idx = ks * 4 + quad;
    const int hh = (idx * 11) >> 5;            // idx/3
    const int off = (idx - hh * 3) * 8;
    #pragma unroll
    for (int m = 0; m < 2; m++) {
      const int T = t0 + w * 32 + m * 16 + l15;
      bf16x8 af = *(const bf16x8*)(og + ((size_t)hh * TOK + T) * 24 + off);
      #pragma unroll
      for (int nt = 0; nt < 6; nt++)
        pacc[m][nt] = __builtin_amdgcn_mfma_f32_16x16x32_bf16(af, bw[nt], pacc[m][nt], 0, 0, 0);
    }
  }

  // ---- phase 2: residual x2 (regs) + LN2 stats (shfl tree) -> s_a bf16 ----
  float x2[2][6][4];
  size_t gg[2][4];
  #pragma unroll
  for (int m = 0; m < 2; m++) {
    #pragma unroll
    for (int r = 0; r < 4; r++) {
      const int T = t0 + w * 32 + m * 16 + quad * 4 + r;
      const int b_ = T >> 8, n = T & 255;
      const int batch = b_ >> 8, wi = b_ & 255;
      const int wd = (wi >> 6) & 3, wh = (wi >> 4) & 3, ww = (wi >> 2) & 3, wt = wi & 3;
      const int aa = (n >> 6) & 3, bb = (n >> 4) & 3, cc = (n >> 2) & 3, dd = n & 3;
      const int sd = (wd * 4 + aa + 2) & 15, sh = (wh * 4 + bb + 2) & 15;
      const int sw = (ww * 4 + cc + 2) & 15, st = (wt * 4 + dd + 2) & 15;
      gg[m][r] = ((((size_t)(batch * 16 + sd) * 16 + sh) * 16 + sw) * 16 + st);
      float s = 0.f, q = 0.f;
      #pragma unroll
      for (int nt = 0; nt < 6; nt++) {
        float v = x[gg[m][r] * 96 + nt * 16 + l15] + pb[nt] + pacc[m][nt][r];
        x2[m][nt][r] = v;
        s += v; q += v * v;
      }
      s += __shfl_xor(s, 1); q += __shfl_xor(q, 1);
      s += __shfl_xor(s, 2); q += __shfl_xor(q, 2);
      s += __shfl_xor(s, 4); q += __shfl_xor(q, 4);
      s += __shfl_xor(s, 8); q += __shfl_xor(q, 8);
      const float mu = s * (1.f / 96.f);
      const float var = q * (1.f / 96.f) - mu * mu;
      const float rs = rsqrtf(fmaxf(var, 0.f) + 1e-5f);
      const int tr = w * 32 + m * 16 + quad * 4 + r;
      #pragma unroll
      for (int nt = 0; nt < 6; nt++)
        s_a[tr * 104 + nt * 16 + l15] =
            (short)f2us((x2[m][nt][r] - mu) * rs * gn[nt] + bn[nt]);
    }
  }
  // s_a rows [w*32, w*32+32) written and read by wave w only -> no barrier.

  // ---- phase 3: MLP ----
  f32x4 acc2[2][6];
  #pragma unroll
  for (int m = 0; m < 2; m++)
    #pragma unroll
    for (int i = 0; i < 6; i++) acc2[m][i] = fz;

  for (int nc = 0; nc < 4; nc++) {
    f32x4 acc1[2][6];
    #pragma unroll
    for (int m = 0; m < 2; m++)
      #pragma unroll
      for (int i = 0; i < 6; i++) acc1[m][i] = fz;
    #pragma unroll
    for (int ks = 0; ks < 3; ks++) {
      bf16x8 bw[6];
      #pragma unroll
      for (int nt = 0; nt < 6; nt++)
        bw[nt] = *(const bf16x8*)(img + IW1 + ((nc * 3 + ks) * 6 + nt) * 512 + l * 8);
      #pragma unroll
      for (int m = 0; m < 2; m++) {
        bf16x8 af = *(const bf16x8*)&s_a[(w * 32 + m * 16 + l15) * 104 + ks * 32 + quad * 8];
        #pragma unroll
        for (int nt = 0; nt < 6; nt++)
          acc1[m][nt] = __builtin_amdgcn_mfma_f32_16x16x32_bf16(af, bw[nt], acc1[m][nt], 0, 0, 0);
      }
    }
    // ---- GELU -> s_h (wave-private rows) ----
    #pragma unroll
    for (int m = 0; m < 2; m++)
      #pragma unroll
      for (int nt = 0; nt < 6; nt++) {
        int col = nt * 16 + l15;
        float bv = fc1_b[nc * 96 + col];
        #pragma unroll
        for (int r = 0; r < 4; r++) {
          float z = acc1[m][nt][r] + bv;
          s_h[(w * 32 + m * 16 + quad * 4 + r) * 104 + col] = (short)f2us(gelu_f(z));
        }
      }
    // ---- GEMM2 partial ----
    #pragma unroll
    for (int ks = 0; ks < 3; ks++) {
      bf16x8 bw[6];
      #pragma unroll
      for (int nt = 0; nt < 6; nt++)
        bw[nt] = *(const bf16x8*)(img + IW2 + ((nc * 3 + ks) * 6 + nt) * 512 + l * 8);
      #pragma unroll
      for (int m = 0; m < 2; m++) {
        bf16x8 af = *(const bf16x8*)&s_h[(w * 32 + m * 16 + l15) * 104 + ks * 32 + quad * 8];
        #pragma unroll
        for (int nt = 0; nt < 6; nt++)
          acc2[m][nt] = __builtin_amdgcn_mfma_f32_16x16x32_bf16(af, bw[nt], acc2[m][nt], 0, 0, 0);
      }
    }
  }

  // ---- epilogue: out = x2 + mlp + fc2_b (spatial scatter) ----
  #pragma unroll
  for (int m = 0; m < 2; m++)
    #pragma unroll
    for (int r = 0; r < 4; r++)
      #pragma unroll
      for (int nt = 0; nt < 6; nt++)
        out[gg[m][r] * 96 + nt * 16 + l15] = x2[m][nt][r] + acc2[m][nt][r] + f2[nt];
}

extern "C" void kernel_launch(void* const* d_in, const int* in_sizes, int n_in,
                              void* d_out, int out_size, void* d_ws, size_t ws_size,
                              hipStream_t stream) {
  const float* x      = (const float*)d_in[0];
  const float* n1g    = (const float*)d_in[2];
  const float* n1b    = (const float*)d_in[3];
  const float* qkv_w  = (const float*)d_in[4];
  const float* qkv_b  = (const float*)d_in[5];
  const float* proj_w = (const float*)d_in[6];
  const float* proj_b = (const float*)d_in[7];
  const float* n2g    = (const float*)d_in[8];
  const float* n2b    = (const float*)d_in[9];
  const float* fc1_w  = (const float*)d_in[10];
  const float* fc1_b  = (const float*)d_in[11];
  const float* fc2_w  = (const float*)d_in[12];
  const float* fc2_b  = (const float*)d_in[13];
  float* out = (float*)d_out;

  // ws: img (227,328 B) | O bf16 head-blocked (25,165,824 B)
  char* ws = (char*)d_ws;
  unsigned short* img = (unsigned short*)ws;
  unsigned short* og  = (unsigned short*)(ws + 227328u);

  k_prepw<<<IMG_SHORTS / 256, 256, 0, stream>>>(fc1_w, fc2_w, qkv_w, proj_w, img);
  k_win<<<BWIN, 256, 0, stream>>>(x, img, n1g, n1b, qkv_b, og);
  k_pm<<<TOK / 128, 256, 0, stream>>>(og, x, img, proj_b, n2g, n2b, fc1_b, fc2_b, out);
}